// Round 6
// baseline (715.786 us; speedup 1.0000x reference)
//
#include <hip/hip_runtime.h>

typedef unsigned int   uint;
typedef unsigned short ushort;
typedef __attribute__((ext_vector_type(8))) short bf16x8;   // 8 bf16 (4 VGPRs)
typedef __attribute__((ext_vector_type(4))) float f32x4;
typedef __attribute__((ext_vector_type(4))) uint  u32x4;    // clang ext-vector:
                                                            // valid for
                                                            // nontemporal builtins

#define N_NODES 50000
#define N_EDGES 800000
#define IN_F    512
#define OUT_F   96
#define SCAN_BLOCKS 196   // 196*256 >= 50000
#define HTPN 6            // threads per node per feature-half (48 feats / 8)
#define HB   1172         // blocks per half: 1172*256 >= 50000*6
#define DEGBINS 256       // counting-sort bins for degree sort

// bf16 helpers (storage-only bf16; math in fp32)
__device__ __forceinline__ float bflo(uint u) { return __uint_as_float(u << 16); }
__device__ __forceinline__ float bfhi(uint u) { return __uint_as_float(u & 0xffff0000u); }
__device__ __forceinline__ uint f2bf(float x) {          // round-to-nearest-even
    uint u = __float_as_uint(x);
    return (u + 0x7fffu + ((u >> 16) & 1u)) >> 16;
}
__device__ __forceinline__ uint pack2bf(float lo, float hi) {
    return f2bf(lo) | (f2bf(hi) << 16);
}

// non-temporal (stream) access: keep L2 free for the h gather panel.
// NOTE: builtins require native ext-vector types, not HIP_vector_type.
__device__ __forceinline__ uint  ntld1(const uint* p)  { return __builtin_nontemporal_load(p); }
__device__ __forceinline__ u32x4 ntld4(const u32x4* p) { return __builtin_nontemporal_load(p); }
__device__ __forceinline__ void  ntst4(u32x4* p, u32x4 v)  { __builtin_nontemporal_store(v, p); }
__device__ __forceinline__ void  ntstf4(f32x4* p, f32x4 v) { __builtin_nontemporal_store(v, p); }

// ---------------------------------------------------------------------------
// w[512,96] fp32 -> wTp chunk-major bf16: wTp[k/32][c][k%32].
// ---------------------------------------------------------------------------
__global__ __launch_bounds__(256) void wt_kernel(const float* __restrict__ w,
                                                 ushort* __restrict__ wTp) {
    int t = blockIdx.x * 256 + threadIdx.x;
    if (t < IN_F * OUT_F) {
        int k = t / OUT_F, c = t - k * OUT_F;
        wTp[(size_t)(k >> 5) * (OUT_F * 32) + c * 32 + (k & 31)] =
            (ushort)f2bf(w[t]);
    }
}

// ---------------------------------------------------------------------------
// MFMA GEMM: supB[N,96](bf16) = x[N,512] @ w[512,96]
// 64-thread blocks (1 wave, 16 rows) -> grid 3125. x prefetched 2 chunks deep;
// w prefetched 1 deep (L2-hot). 6x mfma_16x16x32_bf16 per 32-K chunk.
// ---------------------------------------------------------------------------
__global__ __launch_bounds__(64) void gemm_kernel(const float* __restrict__ x,
                                                  const ushort* __restrict__ wTp,
                                                  ushort* __restrict__ supB) {
    const int lane = threadIdx.x;
    const int m    = lane & 15;
    const int quad = lane >> 4;

    const int row  = blockIdx.x * 16 + m;
    const int arow = (row < N_NODES) ? row : (N_NODES - 1);
    const float*  xp = x + (size_t)arow * IN_F + quad * 8;
    const ushort* wp = wTp + (size_t)m * 32 + quad * 8;   // chunk 0 base

    f32x4 acc[6];
    #pragma unroll
    for (int ct = 0; ct < 6; ++ct) acc[ct] = (f32x4){0.f, 0.f, 0.f, 0.f};

    // prologue: x chunks 0,1 and w chunk 0 in flight
    float4 xA0 = *(const float4*)(xp);
    float4 xB0 = *(const float4*)(xp + 4);
    float4 xA1 = *(const float4*)(xp + 32);
    float4 xB1 = *(const float4*)(xp + 36);
    bf16x8 b[6];
    #pragma unroll
    for (int ct = 0; ct < 6; ++ct)
        b[ct] = *(const bf16x8*)(wp + ct * (16 * 32));

    #pragma unroll
    for (int it = 0; it < 16; ++it) {
        float4 nxa, nxb;
        bf16x8 nb[6];
        if (it + 2 < 16) {
            nxa = *(const float4*)(xp + (it + 2) * 32);
            nxb = *(const float4*)(xp + (it + 2) * 32 + 4);
        }
        if (it + 1 < 16) {
            const ushort* wpn = wp + (size_t)(it + 1) * (OUT_F * 32);
            #pragma unroll
            for (int ct = 0; ct < 6; ++ct)
                nb[ct] = *(const bf16x8*)(wpn + ct * (16 * 32));
        }
        union { uint u[4]; bf16x8 v; } af;
        af.u[0] = pack2bf(xA0.x, xA0.y); af.u[1] = pack2bf(xA0.z, xA0.w);
        af.u[2] = pack2bf(xB0.x, xB0.y); af.u[3] = pack2bf(xB0.z, xB0.w);
        #pragma unroll
        for (int ct = 0; ct < 6; ++ct)
            acc[ct] = __builtin_amdgcn_mfma_f32_16x16x32_bf16(af.v, b[ct],
                                                              acc[ct], 0, 0, 0);
        xA0 = xA1; xB0 = xB1; xA1 = nxa; xB1 = nxb;
        #pragma unroll
        for (int ct = 0; ct < 6; ++ct) b[ct] = nb[ct];
    }

    // C/D layout: col = lane&15 (=m), row = quad*4 + reg
    const int orow0 = blockIdx.x * 16 + quad * 4;
    #pragma unroll
    for (int ct = 0; ct < 6; ++ct) {
        #pragma unroll
        for (int r = 0; r < 4; ++r) {
            int gr = orow0 + r;
            if (gr < N_NODES)
                supB[(size_t)gr * OUT_F + ct * 16 + m] = (ushort)f2bf(acc[ct][r]);
        }
    }
}

// ---------------------------------------------------------------------------
// CSR build: histogram -> hierarchical scan -> scatter (4B packed edges:
// low 16 bits = src node id (50000 < 65536), high 16 bits = bf16 edge val)
// Degree counting-sort via LDS-aggregated histograms (R1 lesson: naive
// global atomics on ~30 hot bins serialized to 131us).
// ---------------------------------------------------------------------------
__global__ void zero_kernel(int* __restrict__ p, int n) {
    int t = blockIdx.x * blockDim.x + threadIdx.x;
    if (t < n) p[t] = 0;
}

__global__ void hist_kernel(const int* __restrict__ dst, int* __restrict__ counts) {
    int e = blockIdx.x * blockDim.x + threadIdx.x;
    if (e < N_EDGES) atomicAdd(&counts[dst[e]], 1);
}

__global__ __launch_bounds__(256) void block_reduce_kernel(const int* __restrict__ counts,
                                                           int* __restrict__ blockSums) {
    __shared__ int s[256];
    int idx = blockIdx.x * 256 + threadIdx.x;
    s[threadIdx.x] = (idx < N_NODES) ? counts[idx] : 0;
    __syncthreads();
    for (int off = 128; off > 0; off >>= 1) {
        if (threadIdx.x < off) s[threadIdx.x] += s[threadIdx.x + off];
        __syncthreads();
    }
    if (threadIdx.x == 0) blockSums[blockIdx.x] = s[0];
}

__global__ __launch_bounds__(256) void scan_sums_kernel(int* __restrict__ blockSums,
                                                        int* __restrict__ blockOffs,
                                                        int* __restrict__ rowstart) {
    __shared__ int s[256];
    int t = threadIdx.x;
    s[t] = (t < SCAN_BLOCKS) ? blockSums[t] : 0;
    __syncthreads();
    for (int off = 1; off < 256; off <<= 1) {
        int v = (t >= off) ? s[t - off] : 0;
        __syncthreads();
        s[t] += v;
        __syncthreads();
    }
    if (t < SCAN_BLOCKS) blockOffs[t] = (t == 0) ? 0 : s[t - 1];
    if (t == 0) rowstart[N_NODES] = s[SCAN_BLOCKS - 1];
}

__global__ __launch_bounds__(256) void block_scan_kernel(const int* __restrict__ counts,
                                                         const int* __restrict__ blockOffs,
                                                         int* __restrict__ rowstart,
                                                         int* __restrict__ cursor,
                                                         int* __restrict__ deghist) {
    __shared__ int s[256];
    __shared__ int lh[DEGBINS];
    int t   = threadIdx.x;
    int idx = blockIdx.x * 256 + t;
    int v   = (idx < N_NODES) ? counts[idx] : 0;
    s[t]  = v;
    lh[t] = 0;
    __syncthreads();
    for (int off = 1; off < 256; off <<= 1) {
        int u = (t >= off) ? s[t - off] : 0;
        __syncthreads();
        s[t] += u;
        __syncthreads();
    }
    if (idx < N_NODES) {
        int excl = blockOffs[blockIdx.x] + s[t] - v;
        rowstart[idx] = excl;
        cursor[idx]   = excl;
        int d = v < (DEGBINS - 1) ? v : (DEGBINS - 1);
        atomicAdd(&lh[d], 1);                 // LDS-aggregated degree histogram
    }
    __syncthreads();
    if (lh[t] > 0) atomicAdd(&deghist[t], lh[t]);   // <=196 adds per address
}

// single block: exclusive scan of the 256 degree bins -> scatter cursors
__global__ __launch_bounds__(256) void degscan_kernel(const int* __restrict__ deghist,
                                                      int* __restrict__ degcur) {
    __shared__ int s[256];
    int t = threadIdx.x;
    int v = deghist[t];
    s[t] = v;
    __syncthreads();
    for (int off = 1; off < 256; off <<= 1) {
        int u = (t >= off) ? s[t - off] : 0;
        __syncthreads();
        s[t] += u;
        __syncthreads();
    }
    degcur[t] = s[t] - v;                     // exclusive prefix
}

// perm[pos] = node ids grouped by degree. Two-level scatter: per-block LDS
// rank + one global atomicAdd per (block,bin) to reserve the output range.
__global__ __launch_bounds__(256) void degscatter_kernel(const int* __restrict__ counts,
                                                         int* __restrict__ degcur,
                                                         int* __restrict__ perm) {
    __shared__ int lhist[DEGBINS];
    __shared__ int lbase[DEGBINS];
    int t = threadIdx.x;
    lhist[t] = 0;
    __syncthreads();
    int i = blockIdx.x * 256 + t;
    int d = 0, lr = 0;
    bool valid = (i < N_NODES);
    if (valid) {
        d  = counts[i];
        if (d > DEGBINS - 1) d = DEGBINS - 1;
        lr = atomicAdd(&lhist[d], 1);         // within-block rank (LDS atomic)
    }
    __syncthreads();
    if (lhist[t] > 0) lbase[t] = atomicAdd(&degcur[t], lhist[t]);
    __syncthreads();
    if (valid) perm[lbase[d] + lr] = i;
}

__global__ void scatter_kernel(const int* __restrict__ src, const int* __restrict__ dst,
                               const float* __restrict__ val, int* __restrict__ cursor,
                               uint* __restrict__ edgeE) {
    int e = blockIdx.x * blockDim.x + threadIdx.x;
    if (e < N_EDGES) {
        int d   = dst[e];
        int pos = atomicAdd(&cursor[d], 1);
        edgeE[pos] = (f2bf(val[e]) << 16) | (uint)src[e];
    }
}

// ---------------------------------------------------------------------------
// Propagation, bf16, FEATURE-HALF PHASED for L2 residency:
//   blocks [0,HB)   : features  0..47 of all nodes
//   blocks [HB,2HB) : features 48..95 of all nodes
// Block-dispatch order gives rough temporal separation, so the live gather
// footprint per phase is ~4.8MB (N*48*2B) instead of 9.6MB -> fits per-XCD
// 4MB L2. All strictly-streaming accesses (edges, sup, outputs) use
// non-temporal hints so they don't evict the gather panel. Gathers (h rows)
// use normal cached loads. Per-(node,feature) FMA order identical to R2 ->
// bitwise-identical results.
// Thread t-of-half -> node-slot i = t/6 -> node perm[i] (degree-sorted:
// uniform trip counts per wave), octet q = t%6 (8 feats within the half).
// ---------------------------------------------------------------------------
__device__ __forceinline__ void acc8(float* a, float v, u32x4 hv) {
    a[0] = fmaf(v, bflo(hv.x), a[0]); a[1] = fmaf(v, bfhi(hv.x), a[1]);
    a[2] = fmaf(v, bflo(hv.y), a[2]); a[3] = fmaf(v, bfhi(hv.y), a[3]);
    a[4] = fmaf(v, bflo(hv.z), a[4]); a[5] = fmaf(v, bfhi(hv.z), a[5]);
    a[6] = fmaf(v, bflo(hv.w), a[6]); a[7] = fmaf(v, bfhi(hv.w), a[7]);
}

template <bool FINAL>
__global__ __launch_bounds__(256) void prop_kernel(const ushort* __restrict__ h,
                                                   const ushort* __restrict__ sup,
                                                   const int* __restrict__ rowstart,
                                                   const uint* __restrict__ edgeE,
                                                   const int* __restrict__ perm,
                                                   ushort* __restrict__ outB,
                                                   float* __restrict__ outF) {
    int half = (blockIdx.x >= HB) ? 1 : 0;
    int t = (blockIdx.x - half * HB) * 256 + threadIdx.x;
    int i = t / HTPN;
    if (i >= N_NODES) return;
    int q = t - i * HTPN;
    int f = half * 48 + q * 8;
    int node = perm[i];

    int start = rowstart[node];
    int end   = rowstart[node + 1];

    size_t o = (size_t)node * OUT_F + f;
    u32x4 sp = ntld4((const u32x4*)(sup + o));  // stream: no L2 pollution

    float a[8] = {0.f, 0.f, 0.f, 0.f, 0.f, 0.f, 0.f, 0.f};
    int e  = start;
    int n8 = (end - start) >> 3;

    uint ed[8];
    if (n8 > 0) {
        #pragma unroll
        for (int u = 0; u < 8; ++u) ed[u] = ntld1(&edgeE[start + u]);
    }
    for (int c = 0; c < n8; ++c) {
        u32x4 hv[8];
        #pragma unroll
        for (int u = 0; u < 8; ++u)
            hv[u] = *(const u32x4*)(h + (size_t)(ed[u] & 0xffffu) * OUT_F + f);
        uint edc[8];
        #pragma unroll
        for (int u = 0; u < 8; ++u) edc[u] = ed[u];
        if (c + 1 < n8) {                     // prefetch next chunk's edges;
            #pragma unroll                    // they ride out the FMA block
            for (int u = 0; u < 8; ++u) ed[u] = ntld1(&edgeE[e + 8 + u]);
        }
        #pragma unroll
        for (int u = 0; u < 8; ++u) acc8(a, bfhi(edc[u]), hv[u]);
        e += 8;
    }

    int rem = end - e;
    if (rem > 0) {                            // one masked 8-wide chunk
        uint edt[8];
        #pragma unroll
        for (int u = 0; u < 8; ++u) {
            int ee = e + u;
            edt[u] = ntld1(&edgeE[(ee < end) ? ee : (end - 1)]);
        }
        u32x4 hv[8];
        #pragma unroll
        for (int u = 0; u < 8; ++u)
            hv[u] = *(const u32x4*)(h + (size_t)(edt[u] & 0xffffu) * OUT_F + f);
        #pragma unroll
        for (int u = 0; u < 8; ++u) {
            float v = (u < rem) ? bfhi(edt[u]) : 0.f;
            acc8(a, v, hv[u]);
        }
    }

    float r[8];
    r[0] = fmaxf(fmaf(a[0], 0.9f, bflo(sp.x) * 0.1f), 0.f);
    r[1] = fmaxf(fmaf(a[1], 0.9f, bfhi(sp.x) * 0.1f), 0.f);
    r[2] = fmaxf(fmaf(a[2], 0.9f, bflo(sp.y) * 0.1f), 0.f);
    r[3] = fmaxf(fmaf(a[3], 0.9f, bfhi(sp.y) * 0.1f), 0.f);
    r[4] = fmaxf(fmaf(a[4], 0.9f, bflo(sp.z) * 0.1f), 0.f);
    r[5] = fmaxf(fmaf(a[5], 0.9f, bfhi(sp.z) * 0.1f), 0.f);
    r[6] = fmaxf(fmaf(a[6], 0.9f, bflo(sp.w) * 0.1f), 0.f);
    r[7] = fmaxf(fmaf(a[7], 0.9f, bfhi(sp.w) * 0.1f), 0.f);

    if (FINAL) {
        ntstf4((f32x4*)(outF + o),     (f32x4){r[0], r[1], r[2], r[3]});
        ntstf4((f32x4*)(outF + o + 4), (f32x4){r[4], r[5], r[6], r[7]});
    } else {
        ntst4((u32x4*)(outB + o),
              (u32x4){pack2bf(r[0], r[1]), pack2bf(r[2], r[3]),
                      pack2bf(r[4], r[5]), pack2bf(r[6], r[7])});
    }
}

// ---------------------------------------------------------------------------
// Buffers: d_out low 9.6MB = supB (gemm out), top 98KB = wTp; final prop
// overwrites d_out fully (supB/wTp dead — props read the supP copy).
// d_in[0] (x, 102.4MB) = scratch AFTER gemm (sole reader of x). d_ws unused.
// Harness restores d_in before every launch.
// ---------------------------------------------------------------------------
extern "C" void kernel_launch(void* const* d_in, const int* in_sizes, int n_in,
                              void* d_out, int out_size, void* d_ws, size_t ws_size,
                              hipStream_t stream) {
    const float* x    = (const float*)d_in[0];
    const float* w    = (const float*)d_in[1];
    const int*   esrc = (const int*)d_in[2];
    const int*   edst = (const int*)d_in[3];
    const float* eval = (const float*)d_in[4];
    float* out = (float*)d_out;

    const size_t supBytes = (size_t)N_NODES * OUT_F * sizeof(ushort);  // 9.6MB
    ushort* supB = (ushort*)d_out;
    ushort* wTp  = (ushort*)((char*)d_out + (size_t)out_size * 4
                             - (size_t)IN_F * OUT_F * sizeof(ushort));

    char*  xb  = (char*)d_in[0];
    size_t off = 0;
    auto alloc = [&](size_t bytes) -> char* {
        char* p = xb + off;
        off = (off + bytes + 255) & ~(size_t)255;
        return p;
    };
    ushort* supP      = (ushort*)alloc(supBytes);                      // 9.6MB
    ushort* hU        = (ushort*)alloc(supBytes);                      // 9.6MB
    ushort* hV        = (ushort*)alloc(supBytes);                      // 9.6MB
    uint*   edgeE     = (uint*)alloc((size_t)N_EDGES * sizeof(uint));  // 3.2MB
    int*    rowstart  = (int*)alloc((N_NODES + 1) * sizeof(int));
    int*    cursor    = (int*)alloc(N_NODES * sizeof(int));
    int*    counts    = (int*)alloc((N_NODES + DEGBINS) * sizeof(int));
    int*    deghist   = counts + N_NODES;
    int*    blockSums = (int*)alloc(SCAN_BLOCKS * sizeof(int));
    int*    blockOffs = (int*)alloc(SCAN_BLOCKS * sizeof(int));
    int*    degcur    = (int*)alloc(DEGBINS * sizeof(int));
    int*    perm      = (int*)alloc(N_NODES * sizeof(int));            // 200KB
    // ~34MB << 102.4MB

    // 1) weights -> bf16 chunk-major (d_out top)
    wt_kernel<<<(IN_F * OUT_F + 255) / 256, 256, 0, stream>>>(w, wTp);

    // 2) MFMA GEMM (last reader of x) -> supB in d_out
    gemm_kernel<<<(N_NODES + 15) / 16, 64, 0, stream>>>(x, wTp, supB);

    // 3) copy supB into x-scratch so final prop can freely write d_out
    (void)hipMemcpyAsync(supP, supB, supBytes, hipMemcpyDeviceToDevice, stream);

    // 4) CSR build + degree counting-sort (x-scratch; safe post-gemm)
    zero_kernel<<<(N_NODES + DEGBINS + 255) / 256, 256, 0, stream>>>(
        counts, N_NODES + DEGBINS);
    hist_kernel<<<(N_EDGES + 255) / 256, 256, 0, stream>>>(edst, counts);
    block_reduce_kernel<<<SCAN_BLOCKS, 256, 0, stream>>>(counts, blockSums);
    scan_sums_kernel<<<1, 256, 0, stream>>>(blockSums, blockOffs, rowstart);
    block_scan_kernel<<<SCAN_BLOCKS, 256, 0, stream>>>(counts, blockOffs,
                                                       rowstart, cursor, deghist);
    degscan_kernel<<<1, 256, 0, stream>>>(deghist, degcur);
    degscatter_kernel<<<SCAN_BLOCKS, 256, 0, stream>>>(counts, degcur, perm);
    scatter_kernel<<<(N_EDGES + 255) / 256, 256, 0, stream>>>(esrc, edst, eval,
                                                              cursor, edgeE);

    // 5) 10 propagation iterations (feature-half phased inside each launch)
    const int pgrid = 2 * HB;
    const ushort* in = supP;
    for (int it = 1; it <= 9; ++it) {
        ushort* o = (it & 1) ? hU : hV;
        prop_kernel<false><<<pgrid, 256, 0, stream>>>(in, supP, rowstart, edgeE,
                                                      perm, o, nullptr);
        in = o;
    }
    prop_kernel<true><<<pgrid, 256, 0, stream>>>(in, supP, rowstart, edgeE,
                                                 perm, nullptr, out);
}

// Round 7
// 639.678 us; speedup vs baseline: 1.1190x; 1.1190x over previous
//
#include <hip/hip_runtime.h>

typedef unsigned int   uint;
typedef unsigned short ushort;
typedef __attribute__((ext_vector_type(8))) short bf16x8;   // 8 bf16 (4 VGPRs)
typedef __attribute__((ext_vector_type(4))) float f32x4;

#define N_NODES 50000
#define N_EDGES 800000
#define IN_F    512
#define OUT_F   96
#define SCAN_BLOCKS 196   // 196*256 >= 50000
#define PTPN 4            // threads per node per panel (32 feats / 8 per lane)
#define PB   782          // blocks per panel launch: 782*256 >= 50000*4
#define PANEL_ELEMS ((size_t)N_NODES * 32)   // bf16 elems per panel
#define DEGBINS 256       // counting-sort bins for degree sort

// bf16 helpers (storage-only bf16; math in fp32)
__device__ __forceinline__ float bflo(uint u) { return __uint_as_float(u << 16); }
__device__ __forceinline__ float bfhi(uint u) { return __uint_as_float(u & 0xffff0000u); }
__device__ __forceinline__ uint f2bf(float x) {          // round-to-nearest-even
    uint u = __float_as_uint(x);
    return (u + 0x7fffu + ((u >> 16) & 1u)) >> 16;
}
__device__ __forceinline__ uint pack2bf(float lo, float hi) {
    return f2bf(lo) | (f2bf(hi) << 16);
}

// ---------------------------------------------------------------------------
// w[512,96] fp32 -> wTp chunk-major bf16: wTp[k/32][c][k%32].
// ---------------------------------------------------------------------------
__global__ __launch_bounds__(256) void wt_kernel(const float* __restrict__ w,
                                                 ushort* __restrict__ wTp) {
    int t = blockIdx.x * 256 + threadIdx.x;
    if (t < IN_F * OUT_F) {
        int k = t / OUT_F, c = t - k * OUT_F;
        wTp[(size_t)(k >> 5) * (OUT_F * 32) + c * 32 + (k & 31)] =
            (ushort)f2bf(w[t]);
    }
}

// ---------------------------------------------------------------------------
// MFMA GEMM: sup = x[N,512] @ w[512,96], written PANEL-MAJOR bf16:
// supB[p][node][pc] with p = col/32, pc = col%32 (3 panels of [N][32]).
// Panel layout makes each 32-feature slice a contiguous 3.2MB block so the
// per-panel prop launches get an L2-resident gather working set.
// ---------------------------------------------------------------------------
__global__ __launch_bounds__(64) void gemm_kernel(const float* __restrict__ x,
                                                  const ushort* __restrict__ wTp,
                                                  ushort* __restrict__ supB) {
    const int lane = threadIdx.x;
    const int m    = lane & 15;
    const int quad = lane >> 4;

    const int row  = blockIdx.x * 16 + m;
    const int arow = (row < N_NODES) ? row : (N_NODES - 1);
    const float*  xp = x + (size_t)arow * IN_F + quad * 8;
    const ushort* wp = wTp + (size_t)m * 32 + quad * 8;   // chunk 0 base

    f32x4 acc[6];
    #pragma unroll
    for (int ct = 0; ct < 6; ++ct) acc[ct] = (f32x4){0.f, 0.f, 0.f, 0.f};

    // prologue: x chunks 0,1 and w chunk 0 in flight
    float4 xA0 = *(const float4*)(xp);
    float4 xB0 = *(const float4*)(xp + 4);
    float4 xA1 = *(const float4*)(xp + 32);
    float4 xB1 = *(const float4*)(xp + 36);
    bf16x8 b[6];
    #pragma unroll
    for (int ct = 0; ct < 6; ++ct)
        b[ct] = *(const bf16x8*)(wp + ct * (16 * 32));

    #pragma unroll
    for (int it = 0; it < 16; ++it) {
        float4 nxa, nxb;
        bf16x8 nb[6];
        if (it + 2 < 16) {
            nxa = *(const float4*)(xp + (it + 2) * 32);
            nxb = *(const float4*)(xp + (it + 2) * 32 + 4);
        }
        if (it + 1 < 16) {
            const ushort* wpn = wp + (size_t)(it + 1) * (OUT_F * 32);
            #pragma unroll
            for (int ct = 0; ct < 6; ++ct)
                nb[ct] = *(const bf16x8*)(wpn + ct * (16 * 32));
        }
        union { uint u[4]; bf16x8 v; } af;
        af.u[0] = pack2bf(xA0.x, xA0.y); af.u[1] = pack2bf(xA0.z, xA0.w);
        af.u[2] = pack2bf(xB0.x, xB0.y); af.u[3] = pack2bf(xB0.z, xB0.w);
        #pragma unroll
        for (int ct = 0; ct < 6; ++ct)
            acc[ct] = __builtin_amdgcn_mfma_f32_16x16x32_bf16(af.v, b[ct],
                                                              acc[ct], 0, 0, 0);
        xA0 = xA1; xB0 = xB1; xA1 = nxa; xB1 = nxb;
        #pragma unroll
        for (int ct = 0; ct < 6; ++ct) b[ct] = nb[ct];
    }

    // C/D layout: col = ct*16 + (lane&15), row = quad*4 + reg
    const int orow0 = blockIdx.x * 16 + quad * 4;
    #pragma unroll
    for (int ct = 0; ct < 6; ++ct) {
        const int col = ct * 16 + m;
        const int p   = col >> 5;             // panel index
        const int pc  = col & 31;             // column within panel
        #pragma unroll
        for (int r = 0; r < 4; ++r) {
            int gr = orow0 + r;
            if (gr < N_NODES)
                supB[(size_t)p * PANEL_ELEMS + (size_t)gr * 32 + pc] =
                    (ushort)f2bf(acc[ct][r]);
        }
    }
}

// ---------------------------------------------------------------------------
// CSR build: histogram -> hierarchical scan -> scatter (4B packed edges:
// low 16 bits = src node id (50000 < 65536), high 16 bits = bf16 edge val)
// Degree counting-sort via LDS-aggregated histograms (R1 lesson: naive
// global atomics on ~30 hot bins serialized to 131us).
// ---------------------------------------------------------------------------
__global__ void zero_kernel(int* __restrict__ p, int n) {
    int t = blockIdx.x * blockDim.x + threadIdx.x;
    if (t < n) p[t] = 0;
}

__global__ void hist_kernel(const int* __restrict__ dst, int* __restrict__ counts) {
    int e = blockIdx.x * blockDim.x + threadIdx.x;
    if (e < N_EDGES) atomicAdd(&counts[dst[e]], 1);
}

__global__ __launch_bounds__(256) void block_reduce_kernel(const int* __restrict__ counts,
                                                           int* __restrict__ blockSums) {
    __shared__ int s[256];
    int idx = blockIdx.x * 256 + threadIdx.x;
    s[threadIdx.x] = (idx < N_NODES) ? counts[idx] : 0;
    __syncthreads();
    for (int off = 128; off > 0; off >>= 1) {
        if (threadIdx.x < off) s[threadIdx.x] += s[threadIdx.x + off];
        __syncthreads();
    }
    if (threadIdx.x == 0) blockSums[blockIdx.x] = s[0];
}

__global__ __launch_bounds__(256) void scan_sums_kernel(int* __restrict__ blockSums,
                                                        int* __restrict__ blockOffs,
                                                        int* __restrict__ rowstart) {
    __shared__ int s[256];
    int t = threadIdx.x;
    s[t] = (t < SCAN_BLOCKS) ? blockSums[t] : 0;
    __syncthreads();
    for (int off = 1; off < 256; off <<= 1) {
        int v = (t >= off) ? s[t - off] : 0;
        __syncthreads();
        s[t] += v;
        __syncthreads();
    }
    if (t < SCAN_BLOCKS) blockOffs[t] = (t == 0) ? 0 : s[t - 1];
    if (t == 0) rowstart[N_NODES] = s[SCAN_BLOCKS - 1];
}

__global__ __launch_bounds__(256) void block_scan_kernel(const int* __restrict__ counts,
                                                         const int* __restrict__ blockOffs,
                                                         int* __restrict__ rowstart,
                                                         int* __restrict__ cursor,
                                                         int* __restrict__ deghist) {
    __shared__ int s[256];
    __shared__ int lh[DEGBINS];
    int t   = threadIdx.x;
    int idx = blockIdx.x * 256 + t;
    int v   = (idx < N_NODES) ? counts[idx] : 0;
    s[t]  = v;
    lh[t] = 0;
    __syncthreads();
    for (int off = 1; off < 256; off <<= 1) {
        int u = (t >= off) ? s[t - off] : 0;
        __syncthreads();
        s[t] += u;
        __syncthreads();
    }
    if (idx < N_NODES) {
        int excl = blockOffs[blockIdx.x] + s[t] - v;
        rowstart[idx] = excl;
        cursor[idx]   = excl;
        int d = v < (DEGBINS - 1) ? v : (DEGBINS - 1);
        atomicAdd(&lh[d], 1);                 // LDS-aggregated degree histogram
    }
    __syncthreads();
    if (lh[t] > 0) atomicAdd(&deghist[t], lh[t]);   // <=196 adds per address
}

// single block: exclusive scan of the 256 degree bins -> scatter cursors
__global__ __launch_bounds__(256) void degscan_kernel(const int* __restrict__ deghist,
                                                      int* __restrict__ degcur) {
    __shared__ int s[256];
    int t = threadIdx.x;
    int v = deghist[t];
    s[t] = v;
    __syncthreads();
    for (int off = 1; off < 256; off <<= 1) {
        int u = (t >= off) ? s[t - off] : 0;
        __syncthreads();
        s[t] += u;
        __syncthreads();
    }
    degcur[t] = s[t] - v;                     // exclusive prefix
}

// perm[pos] = node ids grouped by degree. Two-level scatter: per-block LDS
// rank + one global atomicAdd per (block,bin) to reserve the output range.
__global__ __launch_bounds__(256) void degscatter_kernel(const int* __restrict__ counts,
                                                         int* __restrict__ degcur,
                                                         int* __restrict__ perm) {
    __shared__ int lhist[DEGBINS];
    __shared__ int lbase[DEGBINS];
    int t = threadIdx.x;
    lhist[t] = 0;
    __syncthreads();
    int i = blockIdx.x * 256 + t;
    int d = 0, lr = 0;
    bool valid = (i < N_NODES);
    if (valid) {
        d  = counts[i];
        if (d > DEGBINS - 1) d = DEGBINS - 1;
        lr = atomicAdd(&lhist[d], 1);         // within-block rank (LDS atomic)
    }
    __syncthreads();
    if (lhist[t] > 0) lbase[t] = atomicAdd(&degcur[t], lhist[t]);
    __syncthreads();
    if (valid) perm[lbase[d] + lr] = i;
}

__global__ void scatter_kernel(const int* __restrict__ src, const int* __restrict__ dst,
                               const float* __restrict__ val, int* __restrict__ cursor,
                               uint* __restrict__ edgeE) {
    int e = blockIdx.x * blockDim.x + threadIdx.x;
    if (e < N_EDGES) {
        int d   = dst[e];
        int pos = atomicAdd(&cursor[d], 1);
        edgeE[pos] = (f2bf(val[e]) << 16) | (uint)src[e];
    }
}

// ---------------------------------------------------------------------------
// Propagation, bf16, PANEL-SEPARATED: one launch per 32-feature panel.
// h/sup/out are panel-major [3][N][32]; this kernel receives pointers
// already offset to its panel. Gather working set = one 3.2MB contiguous
// panel < 4MB per-XCD L2; the kernel boundary between panel launches gives
// hard temporal separation (R6 lesson: concurrent phases share L2; and the
// 32-feature split is 64B-line-aligned so no line is fetched by 2 panels).
// All loads/stores are normal cached (R6 lesson: nt stores poison the next
// iteration's gather reuse).
// Thread t -> slot i = t/4 -> node perm[i] (degree-sorted: uniform trip
// counts per wave), octet q = t%4 (8 feats). Gathers: 16B per lane, 4 lanes
// cover the 64B panel row. Edge records double-buffered; tail is one masked
// 8-wide chunk (dummy lanes clamp to end-1, val=0). FMA order per
// (node,feature) identical to R2 -> bitwise-identical results.
// ---------------------------------------------------------------------------
__device__ __forceinline__ void acc8(float* a, float v, uint4 hv) {
    a[0] = fmaf(v, bflo(hv.x), a[0]); a[1] = fmaf(v, bfhi(hv.x), a[1]);
    a[2] = fmaf(v, bflo(hv.y), a[2]); a[3] = fmaf(v, bfhi(hv.y), a[3]);
    a[4] = fmaf(v, bflo(hv.z), a[4]); a[5] = fmaf(v, bfhi(hv.z), a[5]);
    a[6] = fmaf(v, bflo(hv.w), a[6]); a[7] = fmaf(v, bfhi(hv.w), a[7]);
}

template <bool FINAL>
__global__ __launch_bounds__(256) void prop_kernel(const ushort* __restrict__ h,
                                                   const ushort* __restrict__ sup,
                                                   const int* __restrict__ rowstart,
                                                   const uint* __restrict__ edgeE,
                                                   const int* __restrict__ perm,
                                                   ushort* __restrict__ outB,
                                                   float* __restrict__ outF,
                                                   int panel) {
    int t = blockIdx.x * 256 + threadIdx.x;
    int i = t >> 2;
    if (i >= N_NODES) return;
    int q = t & 3;
    int f = q * 8;                            // feature offset within panel
    int node = perm[i];

    int start = rowstart[node];
    int end   = rowstart[node + 1];

    size_t o = (size_t)node * 32 + f;
    uint4 sp = *(const uint4*)(sup + o);      // prefetch: hides epilogue latency

    float a[8] = {0.f, 0.f, 0.f, 0.f, 0.f, 0.f, 0.f, 0.f};
    int e  = start;
    int n8 = (end - start) >> 3;

    uint ed[8];
    if (n8 > 0) {
        #pragma unroll
        for (int u = 0; u < 8; ++u) ed[u] = edgeE[start + u];
    }
    for (int c = 0; c < n8; ++c) {
        uint4 hv[8];
        #pragma unroll
        for (int u = 0; u < 8; ++u)
            hv[u] = *(const uint4*)(h + (size_t)(ed[u] & 0xffffu) * 32 + f);
        uint edc[8];
        #pragma unroll
        for (int u = 0; u < 8; ++u) edc[u] = ed[u];
        if (c + 1 < n8) {                     // prefetch next chunk's edges;
            #pragma unroll                    // they ride out the FMA block
            for (int u = 0; u < 8; ++u) ed[u] = edgeE[e + 8 + u];
        }
        #pragma unroll
        for (int u = 0; u < 8; ++u) acc8(a, bfhi(edc[u]), hv[u]);
        e += 8;
    }

    int rem = end - e;
    if (rem > 0) {                            // one masked 8-wide chunk
        uint edt[8];
        #pragma unroll
        for (int u = 0; u < 8; ++u) {
            int ee = e + u;
            edt[u] = edgeE[(ee < end) ? ee : (end - 1)];
        }
        uint4 hv[8];
        #pragma unroll
        for (int u = 0; u < 8; ++u)
            hv[u] = *(const uint4*)(h + (size_t)(edt[u] & 0xffffu) * 32 + f);
        #pragma unroll
        for (int u = 0; u < 8; ++u) {
            float v = (u < rem) ? bfhi(edt[u]) : 0.f;
            acc8(a, v, hv[u]);
        }
    }

    float r[8];
    r[0] = fmaxf(fmaf(a[0], 0.9f, bflo(sp.x) * 0.1f), 0.f);
    r[1] = fmaxf(fmaf(a[1], 0.9f, bfhi(sp.x) * 0.1f), 0.f);
    r[2] = fmaxf(fmaf(a[2], 0.9f, bflo(sp.y) * 0.1f), 0.f);
    r[3] = fmaxf(fmaf(a[3], 0.9f, bfhi(sp.y) * 0.1f), 0.f);
    r[4] = fmaxf(fmaf(a[4], 0.9f, bflo(sp.z) * 0.1f), 0.f);
    r[5] = fmaxf(fmaf(a[5], 0.9f, bfhi(sp.z) * 0.1f), 0.f);
    r[6] = fmaxf(fmaf(a[6], 0.9f, bflo(sp.w) * 0.1f), 0.f);
    r[7] = fmaxf(fmaf(a[7], 0.9f, bfhi(sp.w) * 0.1f), 0.f);

    if (FINAL) {
        float* op = outF + (size_t)node * OUT_F + panel * 32 + f;
        *(float4*)(op)     = make_float4(r[0], r[1], r[2], r[3]);
        *(float4*)(op + 4) = make_float4(r[4], r[5], r[6], r[7]);
    } else {
        *(uint4*)(outB + o) = make_uint4(pack2bf(r[0], r[1]), pack2bf(r[2], r[3]),
                                         pack2bf(r[4], r[5]), pack2bf(r[6], r[7]));
    }
}

// ---------------------------------------------------------------------------
// Buffers: d_out low 9.6MB = supB panels (gemm out), top 98KB = wTp; final
// props overwrite d_out fully (supB/wTp dead — props read the supP copy).
// d_in[0] (x, 102.4MB) = scratch AFTER gemm (sole reader of x). d_ws unused.
// Harness restores d_in before every launch.
// ---------------------------------------------------------------------------
extern "C" void kernel_launch(void* const* d_in, const int* in_sizes, int n_in,
                              void* d_out, int out_size, void* d_ws, size_t ws_size,
                              hipStream_t stream) {
    const float* x    = (const float*)d_in[0];
    const float* w    = (const float*)d_in[1];
    const int*   esrc = (const int*)d_in[2];
    const int*   edst = (const int*)d_in[3];
    const float* eval = (const float*)d_in[4];
    float* out = (float*)d_out;

    const size_t supBytes = (size_t)N_NODES * OUT_F * sizeof(ushort);  // 9.6MB
    ushort* supB = (ushort*)d_out;            // panel-major [3][N][32]
    ushort* wTp  = (ushort*)((char*)d_out + (size_t)out_size * 4
                             - (size_t)IN_F * OUT_F * sizeof(ushort));

    char*  xb  = (char*)d_in[0];
    size_t off = 0;
    auto alloc = [&](size_t bytes) -> char* {
        char* p = xb + off;
        off = (off + bytes + 255) & ~(size_t)255;
        return p;
    };
    ushort* supP      = (ushort*)alloc(supBytes);   // panel-major [3][N][32]
    ushort* hU        = (ushort*)alloc(supBytes);   // panel-major
    ushort* hV        = (ushort*)alloc(supBytes);   // panel-major
    uint*   edgeE     = (uint*)alloc((size_t)N_EDGES * sizeof(uint));  // 3.2MB
    int*    rowstart  = (int*)alloc((N_NODES + 1) * sizeof(int));
    int*    cursor    = (int*)alloc(N_NODES * sizeof(int));
    int*    counts    = (int*)alloc((N_NODES + DEGBINS) * sizeof(int));
    int*    deghist   = counts + N_NODES;
    int*    blockSums = (int*)alloc(SCAN_BLOCKS * sizeof(int));
    int*    blockOffs = (int*)alloc(SCAN_BLOCKS * sizeof(int));
    int*    degcur    = (int*)alloc(DEGBINS * sizeof(int));
    int*    perm      = (int*)alloc(N_NODES * sizeof(int));            // 200KB
    // ~34MB << 102.4MB

    // 1) weights -> bf16 chunk-major (d_out top)
    wt_kernel<<<(IN_F * OUT_F + 255) / 256, 256, 0, stream>>>(w, wTp);

    // 2) MFMA GEMM (last reader of x) -> supB panels in d_out
    gemm_kernel<<<(N_NODES + 15) / 16, 64, 0, stream>>>(x, wTp, supB);

    // 3) copy supB into x-scratch so final props can freely write d_out
    (void)hipMemcpyAsync(supP, supB, supBytes, hipMemcpyDeviceToDevice, stream);

    // 4) CSR build + degree counting-sort (x-scratch; safe post-gemm)
    zero_kernel<<<(N_NODES + DEGBINS + 255) / 256, 256, 0, stream>>>(
        counts, N_NODES + DEGBINS);
    hist_kernel<<<(N_EDGES + 255) / 256, 256, 0, stream>>>(edst, counts);
    block_reduce_kernel<<<SCAN_BLOCKS, 256, 0, stream>>>(counts, blockSums);
    scan_sums_kernel<<<1, 256, 0, stream>>>(blockSums, blockOffs, rowstart);
    block_scan_kernel<<<SCAN_BLOCKS, 256, 0, stream>>>(counts, blockOffs,
                                                       rowstart, cursor, deghist);
    degscan_kernel<<<1, 256, 0, stream>>>(deghist, degcur);
    degscatter_kernel<<<SCAN_BLOCKS, 256, 0, stream>>>(counts, degcur, perm);
    scatter_kernel<<<(N_EDGES + 255) / 256, 256, 0, stream>>>(esrc, edst, eval,
                                                              cursor, edgeE);

    // 5) 10 propagation iterations, 3 line-aligned panel launches each.
    //    Stream ordering hard-separates panels -> 3.2MB L2-resident gathers.
    const ushort* in = supP;
    for (int it = 1; it <= 9; ++it) {
        ushort* o = (it & 1) ? hU : hV;
        for (int p = 0; p < 3; ++p) {
            prop_kernel<false><<<PB, 256, 0, stream>>>(
                in + p * PANEL_ELEMS, supP + p * PANEL_ELEMS, rowstart, edgeE,
                perm, o + p * PANEL_ELEMS, nullptr, p);
        }
        in = o;
    }
    for (int p = 0; p < 3; ++p) {
        prop_kernel<true><<<PB, 256, 0, stream>>>(
            in + p * PANEL_ELEMS, supP + p * PANEL_ELEMS, rowstart, edgeE,
            perm, nullptr, out, p);
    }
}

// Round 9
// 564.897 us; speedup vs baseline: 1.2671x; 1.1324x over previous
//
#include <hip/hip_runtime.h>

typedef unsigned int   uint;
typedef unsigned short ushort;
typedef __attribute__((ext_vector_type(8))) short bf16x8;   // 8 bf16 (4 VGPRs)
typedef __attribute__((ext_vector_type(4))) float f32x4;

#define N_NODES 50000
#define N_EDGES 800000
#define IN_F    512
#define OUT_F   96
#define SCAN_BLOCKS 196   // 196*256 >= 50000
#define TPN 12            // threads per node in prop (96 feats / 8 per lane)
#define DEGBINS 256       // counting-sort bins for degree sort

// bf16 helpers (storage-only bf16; math in fp32)
__device__ __forceinline__ float bflo(uint u) { return __uint_as_float(u << 16); }
__device__ __forceinline__ float bfhi(uint u) { return __uint_as_float(u & 0xffff0000u); }
__device__ __forceinline__ uint f2bf(float x) {          // round-to-nearest-even
    uint u = __float_as_uint(x);
    return (u + 0x7fffu + ((u >> 16) & 1u)) >> 16;
}
__device__ __forceinline__ uint pack2bf(float lo, float hi) {
    return f2bf(lo) | (f2bf(hi) << 16);
}

// nt LOAD for the read-once-per-kernel edge stream only (R6 lesson: nt STORES
// on inter-iteration data poison reuse; loads on streaming data are safe).
__device__ __forceinline__ uint ntld1(const uint* p) { return __builtin_nontemporal_load(p); }

// ---------------------------------------------------------------------------
// w[512,96] fp32 -> wTp chunk-major bf16: wTp[k/32][c][k%32].
// ---------------------------------------------------------------------------
__global__ __launch_bounds__(256) void wt_kernel(const float* __restrict__ w,
                                                 ushort* __restrict__ wTp) {
    int t = blockIdx.x * 256 + threadIdx.x;
    if (t < IN_F * OUT_F) {
        int k = t / OUT_F, c = t - k * OUT_F;
        wTp[(size_t)(k >> 5) * (OUT_F * 32) + c * 32 + (k & 31)] =
            (ushort)f2bf(w[t]);
    }
}

// ---------------------------------------------------------------------------
// MFMA GEMM: supB[N,96](bf16) = x[N,512] @ w[512,96]  (row-major, R2-exact)
// ---------------------------------------------------------------------------
__global__ __launch_bounds__(64) void gemm_kernel(const float* __restrict__ x,
                                                  const ushort* __restrict__ wTp,
                                                  ushort* __restrict__ supB) {
    const int lane = threadIdx.x;
    const int m    = lane & 15;
    const int quad = lane >> 4;

    const int row  = blockIdx.x * 16 + m;
    const int arow = (row < N_NODES) ? row : (N_NODES - 1);
    const float*  xp = x + (size_t)arow * IN_F + quad * 8;
    const ushort* wp = wTp + (size_t)m * 32 + quad * 8;   // chunk 0 base

    f32x4 acc[6];
    #pragma unroll
    for (int ct = 0; ct < 6; ++ct) acc[ct] = (f32x4){0.f, 0.f, 0.f, 0.f};

    // prologue: x chunks 0,1 and w chunk 0 in flight
    float4 xA0 = *(const float4*)(xp);
    float4 xB0 = *(const float4*)(xp + 4);
    float4 xA1 = *(const float4*)(xp + 32);
    float4 xB1 = *(const float4*)(xp + 36);
    bf16x8 b[6];
    #pragma unroll
    for (int ct = 0; ct < 6; ++ct)
        b[ct] = *(const bf16x8*)(wp + ct * (16 * 32));

    #pragma unroll
    for (int it = 0; it < 16; ++it) {
        float4 nxa, nxb;
        bf16x8 nb[6];
        if (it + 2 < 16) {
            nxa = *(const float4*)(xp + (it + 2) * 32);
            nxb = *(const float4*)(xp + (it + 2) * 32 + 4);
        }
        if (it + 1 < 16) {
            const ushort* wpn = wp + (size_t)(it + 1) * (OUT_F * 32);
            #pragma unroll
            for (int ct = 0; ct < 6; ++ct)
                nb[ct] = *(const bf16x8*)(wpn + ct * (16 * 32));
        }
        union { uint u[4]; bf16x8 v; } af;
        af.u[0] = pack2bf(xA0.x, xA0.y); af.u[1] = pack2bf(xA0.z, xA0.w);
        af.u[2] = pack2bf(xB0.x, xB0.y); af.u[3] = pack2bf(xB0.z, xB0.w);
        #pragma unroll
        for (int ct = 0; ct < 6; ++ct)
            acc[ct] = __builtin_amdgcn_mfma_f32_16x16x32_bf16(af.v, b[ct],
                                                              acc[ct], 0, 0, 0);
        xA0 = xA1; xB0 = xB1; xA1 = nxa; xB1 = nxb;
        #pragma unroll
        for (int ct = 0; ct < 6; ++ct) b[ct] = nb[ct];
    }

    // C/D layout: col = lane&15 (=m), row = quad*4 + reg
    const int orow0 = blockIdx.x * 16 + quad * 4;
    #pragma unroll
    for (int ct = 0; ct < 6; ++ct) {
        #pragma unroll
        for (int r = 0; r < 4; ++r) {
            int gr = orow0 + r;
            if (gr < N_NODES)
                supB[(size_t)gr * OUT_F + ct * 16 + m] = (ushort)f2bf(acc[ct][r]);
        }
    }
}

// ---------------------------------------------------------------------------
// CSR build: histogram -> hierarchical scan -> scatter (4B packed edges:
// low 16 bits = src node id (50000 < 65536), high 16 bits = bf16 edge val)
// Degree counting-sort via LDS-aggregated histograms (R1 lesson: naive
// global atomics on ~30 hot bins serialized to 131us).
// ---------------------------------------------------------------------------
__global__ void zero_kernel(int* __restrict__ p, int n) {
    int t = blockIdx.x * blockDim.x + threadIdx.x;
    if (t < n) p[t] = 0;
}

__global__ void hist_kernel(const int* __restrict__ dst, int* __restrict__ counts) {
    int e = blockIdx.x * blockDim.x + threadIdx.x;
    if (e < N_EDGES) atomicAdd(&counts[dst[e]], 1);
}

__global__ __launch_bounds__(256) void block_reduce_kernel(const int* __restrict__ counts,
                                                           int* __restrict__ blockSums) {
    __shared__ int s[256];
    int idx = blockIdx.x * 256 + threadIdx.x;
    s[threadIdx.x] = (idx < N_NODES) ? counts[idx] : 0;
    __syncthreads();
    for (int off = 128; off > 0; off >>= 1) {
        if (threadIdx.x < off) s[threadIdx.x] += s[threadIdx.x + off];
        __syncthreads();
    }
    if (threadIdx.x == 0) blockSums[blockIdx.x] = s[0];
}

__global__ __launch_bounds__(256) void scan_sums_kernel(int* __restrict__ blockSums,
                                                        int* __restrict__ blockOffs,
                                                        int* __restrict__ rowstart) {
    __shared__ int s[256];
    int t = threadIdx.x;
    s[t] = (t < SCAN_BLOCKS) ? blockSums[t] : 0;
    __syncthreads();
    for (int off = 1; off < 256; off <<= 1) {
        int v = (t >= off) ? s[t - off] : 0;
        __syncthreads();
        s[t] += v;
        __syncthreads();
    }
    if (t < SCAN_BLOCKS) blockOffs[t] = (t == 0) ? 0 : s[t - 1];
    if (t == 0) rowstart[N_NODES] = s[SCAN_BLOCKS - 1];
}

__global__ __launch_bounds__(256) void block_scan_kernel(const int* __restrict__ counts,
                                                         const int* __restrict__ blockOffs,
                                                         int* __restrict__ rowstart,
                                                         int* __restrict__ cursor,
                                                         int* __restrict__ deghist) {
    __shared__ int s[256];
    __shared__ int lh[DEGBINS];
    int t   = threadIdx.x;
    int idx = blockIdx.x * 256 + t;
    int v   = (idx < N_NODES) ? counts[idx] : 0;
    s[t]  = v;
    lh[t] = 0;
    __syncthreads();
    for (int off = 1; off < 256; off <<= 1) {
        int u = (t >= off) ? s[t - off] : 0;
        __syncthreads();
        s[t] += u;
        __syncthreads();
    }
    if (idx < N_NODES) {
        int excl = blockOffs[blockIdx.x] + s[t] - v;
        rowstart[idx] = excl;
        cursor[idx]   = excl;
        int d = v < (DEGBINS - 1) ? v : (DEGBINS - 1);
        atomicAdd(&lh[d], 1);                 // LDS-aggregated degree histogram
    }
    __syncthreads();
    if (lh[t] > 0) atomicAdd(&deghist[t], lh[t]);   // <=196 adds per address
}

// single block: exclusive scan of the 256 degree bins -> scatter cursors
__global__ __launch_bounds__(256) void degscan_kernel(const int* __restrict__ deghist,
                                                      int* __restrict__ degcur) {
    __shared__ int s[256];
    int t = threadIdx.x;
    int v = deghist[t];
    s[t] = v;
    __syncthreads();
    for (int off = 1; off < 256; off <<= 1) {
        int u = (t >= off) ? s[t - off] : 0;
        __syncthreads();
        s[t] += u;
        __syncthreads();
    }
    degcur[t] = s[t] - v;                     // exclusive prefix
}

// perm[pos] = node ids grouped by degree. Two-level scatter: per-block LDS
// rank + one global atomicAdd per (block,bin) to reserve the output range.
__global__ __launch_bounds__(256) void degscatter_kernel(const int* __restrict__ counts,
                                                         int* __restrict__ degcur,
                                                         int* __restrict__ perm) {
    __shared__ int lhist[DEGBINS];
    __shared__ int lbase[DEGBINS];
    int t = threadIdx.x;
    lhist[t] = 0;
    __syncthreads();
    int i = blockIdx.x * 256 + t;
    int d = 0, lr = 0;
    bool valid = (i < N_NODES);
    if (valid) {
        d  = counts[i];
        if (d > DEGBINS - 1) d = DEGBINS - 1;
        lr = atomicAdd(&lhist[d], 1);         // within-block rank (LDS atomic)
    }
    __syncthreads();
    if (lhist[t] > 0) lbase[t] = atomicAdd(&degcur[t], lhist[t]);
    __syncthreads();
    if (valid) perm[lbase[d] + lr] = i;
}

__global__ void scatter_kernel(const int* __restrict__ src, const int* __restrict__ dst,
                               const float* __restrict__ val, int* __restrict__ cursor,
                               uint* __restrict__ edgeE) {
    int e = blockIdx.x * blockDim.x + threadIdx.x;
    if (e < N_EDGES) {
        int d   = dst[e];
        int pos = atomicAdd(&cursor[d], 1);
        edgeE[pos] = (f2bf(val[e]) << 16) | (uint)src[e];
    }
}

// ---------------------------------------------------------------------------
// Propagation (R2-exact structure): thread t -> sorted-slot i = t/12 ->
// node perm[i] (degree-sorted: uniform trip counts per wave), octet q = t%12.
// Main loop: 8-edge chunks, edge records double-buffered. Tail: one masked
// 8-wide chunk. Single delta vs R2: edge-record loads are NON-TEMPORAL
// (read-once stream within a launch; keeps L2 for the h gather panel).
// FMA order per (node,feature) identical to R2 -> bitwise-identical output.
// ---------------------------------------------------------------------------
__device__ __forceinline__ void acc8(float* a, float v, uint4 hv) {
    a[0] = fmaf(v, bflo(hv.x), a[0]); a[1] = fmaf(v, bfhi(hv.x), a[1]);
    a[2] = fmaf(v, bflo(hv.y), a[2]); a[3] = fmaf(v, bfhi(hv.y), a[3]);
    a[4] = fmaf(v, bflo(hv.z), a[4]); a[5] = fmaf(v, bfhi(hv.z), a[5]);
    a[6] = fmaf(v, bflo(hv.w), a[6]); a[7] = fmaf(v, bfhi(hv.w), a[7]);
}

template <bool FINAL>
__global__ __launch_bounds__(256) void prop_kernel(const ushort* __restrict__ h,
                                                   const ushort* __restrict__ sup,
                                                   const int* __restrict__ rowstart,
                                                   const uint* __restrict__ edgeE,
                                                   const int* __restrict__ perm,
                                                   ushort* __restrict__ outB,
                                                   float* __restrict__ outF) {
    int t = blockIdx.x * 256 + threadIdx.x;
    int i = t / TPN;
    if (i >= N_NODES) return;
    int q = t - i * TPN;
    int f = q * 8;
    int node = perm[i];

    int start = rowstart[node];
    int end   = rowstart[node + 1];

    size_t o = (size_t)node * OUT_F + f;
    uint4 sp = *(const uint4*)(sup + o);      // prefetch: hides epilogue latency

    float a[8] = {0.f, 0.f, 0.f, 0.f, 0.f, 0.f, 0.f, 0.f};
    int e  = start;
    int n8 = (end - start) >> 3;

    uint ed[8];
    if (n8 > 0) {
        #pragma unroll
        for (int u = 0; u < 8; ++u) ed[u] = ntld1(&edgeE[start + u]);
    }
    for (int c = 0; c < n8; ++c) {
        uint4 hv[8];
        #pragma unroll
        for (int u = 0; u < 8; ++u)
            hv[u] = *(const uint4*)(h + (size_t)(ed[u] & 0xffffu) * OUT_F + f);
        uint edc[8];
        #pragma unroll
        for (int u = 0; u < 8; ++u) edc[u] = ed[u];
        if (c + 1 < n8) {                     // prefetch next chunk's edges;
            #pragma unroll                    // they ride out the FMA block
            for (int u = 0; u < 8; ++u) ed[u] = ntld1(&edgeE[e + 8 + u]);
        }
        #pragma unroll
        for (int u = 0; u < 8; ++u) acc8(a, bfhi(edc[u]), hv[u]);
        e += 8;
    }

    int rem = end - e;
    if (rem > 0) {                            // one masked 8-wide chunk
        uint edt[8];
        #pragma unroll
        for (int u = 0; u < 8; ++u) {
            int ee = e + u;
            edt[u] = ntld1(&edgeE[(ee < end) ? ee : (end - 1)]);
        }
        uint4 hv[8];
        #pragma unroll
        for (int u = 0; u < 8; ++u)
            hv[u] = *(const uint4*)(h + (size_t)(edt[u] & 0xffffu) * OUT_F + f);
        #pragma unroll
        for (int u = 0; u < 8; ++u) {
            float v = (u < rem) ? bfhi(edt[u]) : 0.f;
            acc8(a, v, hv[u]);
        }
    }

    float r[8];
    r[0] = fmaxf(fmaf(a[0], 0.9f, bflo(sp.x) * 0.1f), 0.f);
    r[1] = fmaxf(fmaf(a[1], 0.9f, bfhi(sp.x) * 0.1f), 0.f);
    r[2] = fmaxf(fmaf(a[2], 0.9f, bflo(sp.y) * 0.1f), 0.f);
    r[3] = fmaxf(fmaf(a[3], 0.9f, bfhi(sp.y) * 0.1f), 0.f);
    r[4] = fmaxf(fmaf(a[4], 0.9f, bflo(sp.z) * 0.1f), 0.f);
    r[5] = fmaxf(fmaf(a[5], 0.9f, bfhi(sp.z) * 0.1f), 0.f);
    r[6] = fmaxf(fmaf(a[6], 0.9f, bflo(sp.w) * 0.1f), 0.f);
    r[7] = fmaxf(fmaf(a[7], 0.9f, bfhi(sp.w) * 0.1f), 0.f);

    if (FINAL) {
        *(float4*)(outF + o)     = make_float4(r[0], r[1], r[2], r[3]);
        *(float4*)(outF + o + 4) = make_float4(r[4], r[5], r[6], r[7]);
    } else {
        *(uint4*)(outB + o) = make_uint4(pack2bf(r[0], r[1]), pack2bf(r[2], r[3]),
                                         pack2bf(r[4], r[5]), pack2bf(r[6], r[7]));
    }
}

// ---------------------------------------------------------------------------
// Buffers: d_out low 9.6MB = supB (gemm out), top 98KB = wTp; final prop
// overwrites d_out fully (supB/wTp dead — props read the supP copy).
// d_in[0] (x, 102.4MB) = scratch AFTER gemm (sole reader of x). d_ws unused.
// Harness restores d_in before every launch.
// ---------------------------------------------------------------------------
extern "C" void kernel_launch(void* const* d_in, const int* in_sizes, int n_in,
                              void* d_out, int out_size, void* d_ws, size_t ws_size,
                              hipStream_t stream) {
    const float* x    = (const float*)d_in[0];
    const float* w    = (const float*)d_in[1];
    const int*   esrc = (const int*)d_in[2];
    const int*   edst = (const int*)d_in[3];
    const float* eval = (const float*)d_in[4];
    float* out = (float*)d_out;

    const size_t supBytes = (size_t)N_NODES * OUT_F * sizeof(ushort);  // 9.6MB
    ushort* supB = (ushort*)d_out;
    ushort* wTp  = (ushort*)((char*)d_out + (size_t)out_size * 4
                             - (size_t)IN_F * OUT_F * sizeof(ushort));

    char*  xb  = (char*)d_in[0];
    size_t off = 0;
    auto alloc = [&](size_t bytes) -> char* {
        char* p = xb + off;
        off = (off + bytes + 255) & ~(size_t)255;
        return p;
    };
    ushort* supP      = (ushort*)alloc(supBytes);                      // 9.6MB
    ushort* hU        = (ushort*)alloc(supBytes);                      // 9.6MB
    ushort* hV        = (ushort*)alloc(supBytes);                      // 9.6MB
    uint*   edgeE     = (uint*)alloc((size_t)N_EDGES * sizeof(uint));  // 3.2MB
    int*    rowstart  = (int*)alloc((N_NODES + 1) * sizeof(int));
    int*    cursor    = (int*)alloc(N_NODES * sizeof(int));
    int*    counts    = (int*)alloc((N_NODES + DEGBINS) * sizeof(int));
    int*    deghist   = counts + N_NODES;
    int*    blockSums = (int*)alloc(SCAN_BLOCKS * sizeof(int));
    int*    blockOffs = (int*)alloc(SCAN_BLOCKS * sizeof(int));
    int*    degcur    = (int*)alloc(DEGBINS * sizeof(int));
    int*    perm      = (int*)alloc(N_NODES * sizeof(int));            // 200KB
    // ~34MB << 102.4MB

    // 1) weights -> bf16 chunk-major (d_out top)
    wt_kernel<<<(IN_F * OUT_F + 255) / 256, 256, 0, stream>>>(w, wTp);

    // 2) MFMA GEMM (last reader of x) -> supB in d_out
    gemm_kernel<<<(N_NODES + 15) / 16, 64, 0, stream>>>(x, wTp, supB);

    // 3) copy supB into x-scratch so final prop can freely write d_out
    (void)hipMemcpyAsync(supP, supB, supBytes, hipMemcpyDeviceToDevice, stream);

    // 4) CSR build + degree counting-sort (x-scratch; safe post-gemm)
    zero_kernel<<<(N_NODES + DEGBINS + 255) / 256, 256, 0, stream>>>(
        counts, N_NODES + DEGBINS);
    hist_kernel<<<(N_EDGES + 255) / 256, 256, 0, stream>>>(edst, counts);
    block_reduce_kernel<<<SCAN_BLOCKS, 256, 0, stream>>>(counts, blockSums);
    scan_sums_kernel<<<1, 256, 0, stream>>>(blockSums, blockOffs, rowstart);
    block_scan_kernel<<<SCAN_BLOCKS, 256, 0, stream>>>(counts, blockOffs,
                                                       rowstart, cursor, deghist);
    degscan_kernel<<<1, 256, 0, stream>>>(deghist, degcur);
    degscatter_kernel<<<SCAN_BLOCKS, 256, 0, stream>>>(counts, degcur, perm);
    scatter_kernel<<<(N_EDGES + 255) / 256, 256, 0, stream>>>(esrc, edst, eval,
                                                              cursor, edgeE);

    // 5) 10 propagation iterations: supP -> hU -> hV -> ... -> d_out (fp32)
    const int pgrid = (N_NODES * TPN + 255) / 256;
    const ushort* in = supP;
    for (int it = 1; it <= 9; ++it) {
        ushort* o = (it & 1) ? hU : hV;
        prop_kernel<false><<<pgrid, 256, 0, stream>>>(in, supP, rowstart, edgeE,
                                                      perm, o, nullptr);
        in = o;
    }
    prop_kernel<true><<<pgrid, 256, 0, stream>>>(in, supP, rowstart, edgeE,
                                                 perm, nullptr, out);
}

// Round 10
// 541.082 us; speedup vs baseline: 1.3229x; 1.0440x over previous
//
#include <hip/hip_runtime.h>

typedef unsigned int   uint;
typedef unsigned short ushort;
typedef __attribute__((ext_vector_type(8))) short bf16x8;   // 8 bf16 (4 VGPRs)
typedef __attribute__((ext_vector_type(4))) float f32x4;

#define N_NODES 50000
#define N_EDGES 800000
#define IN_F    512
#define OUT_F   96
#define SCAN_BLOCKS 196   // 196*256 >= 50000
#define TPN 12            // threads per node in prop (96 feats / 8 per lane)
#define DEGBINS 256       // counting-sort bins for degree sort

// bf16 helpers (storage-only bf16; math in fp32)
__device__ __forceinline__ float bflo(uint u) { return __uint_as_float(u << 16); }
__device__ __forceinline__ float bfhi(uint u) { return __uint_as_float(u & 0xffff0000u); }
__device__ __forceinline__ uint f2bf(float x) {          // round-to-nearest-even
    uint u = __float_as_uint(x);
    return (u + 0x7fffu + ((u >> 16) & 1u)) >> 16;
}
__device__ __forceinline__ uint pack2bf(float lo, float hi) {
    return f2bf(lo) | (f2bf(hi) << 16);
}

// ---------------------------------------------------------------------------
// w[512,96] fp32 -> wTp chunk-major bf16: wTp[k/32][c][k%32].
// ---------------------------------------------------------------------------
__global__ __launch_bounds__(256) void wt_kernel(const float* __restrict__ w,
                                                 ushort* __restrict__ wTp) {
    int t = blockIdx.x * 256 + threadIdx.x;
    if (t < IN_F * OUT_F) {
        int k = t / OUT_F, c = t - k * OUT_F;
        wTp[(size_t)(k >> 5) * (OUT_F * 32) + c * 32 + (k & 31)] =
            (ushort)f2bf(w[t]);
    }
}

// ---------------------------------------------------------------------------
// MFMA GEMM: supB[N,96](bf16) = x[N,512] @ w[512,96]  (row-major, R2-exact)
// ---------------------------------------------------------------------------
__global__ __launch_bounds__(64) void gemm_kernel(const float* __restrict__ x,
                                                  const ushort* __restrict__ wTp,
                                                  ushort* __restrict__ supB) {
    const int lane = threadIdx.x;
    const int m    = lane & 15;
    const int quad = lane >> 4;

    const int row  = blockIdx.x * 16 + m;
    const int arow = (row < N_NODES) ? row : (N_NODES - 1);
    const float*  xp = x + (size_t)arow * IN_F + quad * 8;
    const ushort* wp = wTp + (size_t)m * 32 + quad * 8;   // chunk 0 base

    f32x4 acc[6];
    #pragma unroll
    for (int ct = 0; ct < 6; ++ct) acc[ct] = (f32x4){0.f, 0.f, 0.f, 0.f};

    // prologue: x chunks 0,1 and w chunk 0 in flight
    float4 xA0 = *(const float4*)(xp);
    float4 xB0 = *(const float4*)(xp + 4);
    float4 xA1 = *(const float4*)(xp + 32);
    float4 xB1 = *(const float4*)(xp + 36);
    bf16x8 b[6];
    #pragma unroll
    for (int ct = 0; ct < 6; ++ct)
        b[ct] = *(const bf16x8*)(wp + ct * (16 * 32));

    #pragma unroll
    for (int it = 0; it < 16; ++it) {
        float4 nxa, nxb;
        bf16x8 nb[6];
        if (it + 2 < 16) {
            nxa = *(const float4*)(xp + (it + 2) * 32);
            nxb = *(const float4*)(xp + (it + 2) * 32 + 4);
        }
        if (it + 1 < 16) {
            const ushort* wpn = wp + (size_t)(it + 1) * (OUT_F * 32);
            #pragma unroll
            for (int ct = 0; ct < 6; ++ct)
                nb[ct] = *(const bf16x8*)(wpn + ct * (16 * 32));
        }
        union { uint u[4]; bf16x8 v; } af;
        af.u[0] = pack2bf(xA0.x, xA0.y); af.u[1] = pack2bf(xA0.z, xA0.w);
        af.u[2] = pack2bf(xB0.x, xB0.y); af.u[3] = pack2bf(xB0.z, xB0.w);
        #pragma unroll
        for (int ct = 0; ct < 6; ++ct)
            acc[ct] = __builtin_amdgcn_mfma_f32_16x16x32_bf16(af.v, b[ct],
                                                              acc[ct], 0, 0, 0);
        xA0 = xA1; xB0 = xB1; xA1 = nxa; xB1 = nxb;
        #pragma unroll
        for (int ct = 0; ct < 6; ++ct) b[ct] = nb[ct];
    }

    // C/D layout: col = lane&15 (=m), row = quad*4 + reg
    const int orow0 = blockIdx.x * 16 + quad * 4;
    #pragma unroll
    for (int ct = 0; ct < 6; ++ct) {
        #pragma unroll
        for (int r = 0; r < 4; ++r) {
            int gr = orow0 + r;
            if (gr < N_NODES)
                supB[(size_t)gr * OUT_F + ct * 16 + m] = (ushort)f2bf(acc[ct][r]);
        }
    }
}

// ---------------------------------------------------------------------------
// CSR build: histogram -> hierarchical scan -> scatter (4B packed edges:
// low 16 bits = src node id (50000 < 65536), high 16 bits = bf16 edge val)
// Degree counting-sort via LDS-aggregated histograms (R1 lesson: naive
// global atomics on ~30 hot bins serialized to 131us).
// ---------------------------------------------------------------------------
__global__ void zero_kernel(int* __restrict__ p, int n) {
    int t = blockIdx.x * blockDim.x + threadIdx.x;
    if (t < n) p[t] = 0;
}

__global__ void hist_kernel(const int* __restrict__ dst, int* __restrict__ counts) {
    int e = blockIdx.x * blockDim.x + threadIdx.x;
    if (e < N_EDGES) atomicAdd(&counts[dst[e]], 1);
}

__global__ __launch_bounds__(256) void block_reduce_kernel(const int* __restrict__ counts,
                                                           int* __restrict__ blockSums) {
    __shared__ int s[256];
    int idx = blockIdx.x * 256 + threadIdx.x;
    s[threadIdx.x] = (idx < N_NODES) ? counts[idx] : 0;
    __syncthreads();
    for (int off = 128; off > 0; off >>= 1) {
        if (threadIdx.x < off) s[threadIdx.x] += s[threadIdx.x + off];
        __syncthreads();
    }
    if (threadIdx.x == 0) blockSums[blockIdx.x] = s[0];
}

__global__ __launch_bounds__(256) void scan_sums_kernel(int* __restrict__ blockSums,
                                                        int* __restrict__ blockOffs,
                                                        int* __restrict__ rowstart) {
    __shared__ int s[256];
    int t = threadIdx.x;
    s[t] = (t < SCAN_BLOCKS) ? blockSums[t] : 0;
    __syncthreads();
    for (int off = 1; off < 256; off <<= 1) {
        int v = (t >= off) ? s[t - off] : 0;
        __syncthreads();
        s[t] += v;
        __syncthreads();
    }
    if (t < SCAN_BLOCKS) blockOffs[t] = (t == 0) ? 0 : s[t - 1];
    if (t == 0) rowstart[N_NODES] = s[SCAN_BLOCKS - 1];
}

__global__ __launch_bounds__(256) void block_scan_kernel(const int* __restrict__ counts,
                                                         const int* __restrict__ blockOffs,
                                                         int* __restrict__ rowstart,
                                                         int* __restrict__ cursor,
                                                         int* __restrict__ deghist) {
    __shared__ int s[256];
    __shared__ int lh[DEGBINS];
    int t   = threadIdx.x;
    int idx = blockIdx.x * 256 + t;
    int v   = (idx < N_NODES) ? counts[idx] : 0;
    s[t]  = v;
    lh[t] = 0;
    __syncthreads();
    for (int off = 1; off < 256; off <<= 1) {
        int u = (t >= off) ? s[t - off] : 0;
        __syncthreads();
        s[t] += u;
        __syncthreads();
    }
    if (idx < N_NODES) {
        int excl = blockOffs[blockIdx.x] + s[t] - v;
        rowstart[idx] = excl;
        cursor[idx]   = excl;
        int d = v < (DEGBINS - 1) ? v : (DEGBINS - 1);
        atomicAdd(&lh[d], 1);                 // LDS-aggregated degree histogram
    }
    __syncthreads();
    if (lh[t] > 0) atomicAdd(&deghist[t], lh[t]);   // <=196 adds per address
}

// single block: exclusive scan of the 256 degree bins -> scatter cursors
__global__ __launch_bounds__(256) void degscan_kernel(const int* __restrict__ deghist,
                                                      int* __restrict__ degcur) {
    __shared__ int s[256];
    int t = threadIdx.x;
    int v = deghist[t];
    s[t] = v;
    __syncthreads();
    for (int off = 1; off < 256; off <<= 1) {
        int u = (t >= off) ? s[t - off] : 0;
        __syncthreads();
        s[t] += u;
        __syncthreads();
    }
    degcur[t] = s[t] - v;                     // exclusive prefix
}

// perm[pos] = node ids grouped by degree. Two-level scatter: per-block LDS
// rank + one global atomicAdd per (block,bin) to reserve the output range.
__global__ __launch_bounds__(256) void degscatter_kernel(const int* __restrict__ counts,
                                                         int* __restrict__ degcur,
                                                         int* __restrict__ perm) {
    __shared__ int lhist[DEGBINS];
    __shared__ int lbase[DEGBINS];
    int t = threadIdx.x;
    lhist[t] = 0;
    __syncthreads();
    int i = blockIdx.x * 256 + t;
    int d = 0, lr = 0;
    bool valid = (i < N_NODES);
    if (valid) {
        d  = counts[i];
        if (d > DEGBINS - 1) d = DEGBINS - 1;
        lr = atomicAdd(&lhist[d], 1);         // within-block rank (LDS atomic)
    }
    __syncthreads();
    if (lhist[t] > 0) lbase[t] = atomicAdd(&degcur[t], lhist[t]);
    __syncthreads();
    if (valid) perm[lbase[d] + lr] = i;
}

__global__ void scatter_kernel(const int* __restrict__ src, const int* __restrict__ dst,
                               const float* __restrict__ val, int* __restrict__ cursor,
                               uint* __restrict__ edgeE) {
    int e = blockIdx.x * blockDim.x + threadIdx.x;
    if (e < N_EDGES) {
        int d   = dst[e];
        int pos = atomicAdd(&cursor[d], 1);
        edgeE[pos] = (f2bf(val[e]) << 16) | (uint)src[e];
    }
}

// ---------------------------------------------------------------------------
// Propagation (R2 structure + deg<=16 FLAT FAST PATH): thread t -> sorted
// slot i = t/12 -> node perm[i] (degree-sorted waves), octet q = t%12.
//
// FAST PATH (1 <= deg <= 16, ~57% of nodes, wave-coherent thanks to the
// degree sort): issue BOTH 8-edge loads back-to-back, then ALL 16 gathers,
// then all FMAs. Collapses the ed->hv->FMA chain from 2 serialized gather
// round-trips (~2060cy) to 1 (~1460cy) and doubles per-wave gather lines
// in flight (16 vs 8). Dummy lanes clamp to end-1 and use v=0: fmaf(0,x,a)
// == a exactly, so accumulation is bitwise-identical to the chunked order.
// SLOW PATH (deg > 16 or deg == 0): R2-exact chunked loop + masked tail.
// No nt hints anywhere (R9 lesson: edgeE is re-read by all 10 launches).
// ---------------------------------------------------------------------------
__device__ __forceinline__ void acc8(float* a, float v, uint4 hv) {
    a[0] = fmaf(v, bflo(hv.x), a[0]); a[1] = fmaf(v, bfhi(hv.x), a[1]);
    a[2] = fmaf(v, bflo(hv.y), a[2]); a[3] = fmaf(v, bfhi(hv.y), a[3]);
    a[4] = fmaf(v, bflo(hv.z), a[4]); a[5] = fmaf(v, bfhi(hv.z), a[5]);
    a[6] = fmaf(v, bflo(hv.w), a[6]); a[7] = fmaf(v, bfhi(hv.w), a[7]);
}

template <bool FINAL>
__global__ __launch_bounds__(256) void prop_kernel(const ushort* __restrict__ h,
                                                   const ushort* __restrict__ sup,
                                                   const int* __restrict__ rowstart,
                                                   const uint* __restrict__ edgeE,
                                                   const int* __restrict__ perm,
                                                   ushort* __restrict__ outB,
                                                   float* __restrict__ outF) {
    int t = blockIdx.x * 256 + threadIdx.x;
    int i = t / TPN;
    if (i >= N_NODES) return;
    int q = t - i * TPN;
    int f = q * 8;
    int node = perm[i];

    int start = rowstart[node];
    int end   = rowstart[node + 1];
    int deg   = end - start;

    size_t o = (size_t)node * OUT_F + f;
    uint4 sp = *(const uint4*)(sup + o);      // prefetch: hides epilogue latency

    float a[8] = {0.f, 0.f, 0.f, 0.f, 0.f, 0.f, 0.f, 0.f};

    if (deg >= 1 && deg <= 16) {
        // ---- flat fast path: one edge wait + one gather wait total ----
        uint ed[16];
        #pragma unroll
        for (int u = 0; u < 16; ++u) {
            int ee = start + u;
            ed[u] = edgeE[(ee < end) ? ee : (end - 1)];
        }
        uint4 hv[16];
        #pragma unroll
        for (int u = 0; u < 16; ++u)
            hv[u] = *(const uint4*)(h + (size_t)(ed[u] & 0xffffu) * OUT_F + f);
        #pragma unroll
        for (int u = 0; u < 16; ++u) {
            float v = (u < deg) ? bfhi(ed[u]) : 0.f;
            acc8(a, v, hv[u]);
        }
    } else if (deg > 0) {
        // ---- chunked slow path (R2-exact) ----
        int e  = start;
        int n8 = deg >> 3;

        uint ed[8];
        #pragma unroll
        for (int u = 0; u < 8; ++u) ed[u] = edgeE[start + u];
        for (int c = 0; c < n8; ++c) {
            uint4 hv[8];
            #pragma unroll
            for (int u = 0; u < 8; ++u)
                hv[u] = *(const uint4*)(h + (size_t)(ed[u] & 0xffffu) * OUT_F + f);
            uint edc[8];
            #pragma unroll
            for (int u = 0; u < 8; ++u) edc[u] = ed[u];
            if (c + 1 < n8) {                 // prefetch next chunk's edges;
                #pragma unroll                // they ride out the FMA block
                for (int u = 0; u < 8; ++u) ed[u] = edgeE[e + 8 + u];
            }
            #pragma unroll
            for (int u = 0; u < 8; ++u) acc8(a, bfhi(edc[u]), hv[u]);
            e += 8;
        }

        int rem = end - e;
        if (rem > 0) {                        // one masked 8-wide chunk
            uint edt[8];
            #pragma unroll
            for (int u = 0; u < 8; ++u) {
                int ee = e + u;
                edt[u] = edgeE[(ee < end) ? ee : (end - 1)];
            }
            uint4 hv[8];
            #pragma unroll
            for (int u = 0; u < 8; ++u)
                hv[u] = *(const uint4*)(h + (size_t)(edt[u] & 0xffffu) * OUT_F + f);
            #pragma unroll
            for (int u = 0; u < 8; ++u) {
                float v = (u < rem) ? bfhi(edt[u]) : 0.f;
                acc8(a, v, hv[u]);
            }
        }
    }

    float r[8];
    r[0] = fmaxf(fmaf(a[0], 0.9f, bflo(sp.x) * 0.1f), 0.f);
    r[1] = fmaxf(fmaf(a[1], 0.9f, bfhi(sp.x) * 0.1f), 0.f);
    r[2] = fmaxf(fmaf(a[2], 0.9f, bflo(sp.y) * 0.1f), 0.f);
    r[3] = fmaxf(fmaf(a[3], 0.9f, bfhi(sp.y) * 0.1f), 0.f);
    r[4] = fmaxf(fmaf(a[4], 0.9f, bflo(sp.z) * 0.1f), 0.f);
    r[5] = fmaxf(fmaf(a[5], 0.9f, bfhi(sp.z) * 0.1f), 0.f);
    r[6] = fmaxf(fmaf(a[6], 0.9f, bflo(sp.w) * 0.1f), 0.f);
    r[7] = fmaxf(fmaf(a[7], 0.9f, bfhi(sp.w) * 0.1f), 0.f);

    if (FINAL) {
        *(float4*)(outF + o)     = make_float4(r[0], r[1], r[2], r[3]);
        *(float4*)(outF + o + 4) = make_float4(r[4], r[5], r[6], r[7]);
    } else {
        *(uint4*)(outB + o) = make_uint4(pack2bf(r[0], r[1]), pack2bf(r[2], r[3]),
                                         pack2bf(r[4], r[5]), pack2bf(r[6], r[7]));
    }
}

// ---------------------------------------------------------------------------
// Buffers: d_out low 9.6MB = supB (gemm out), top 98KB = wTp; final prop
// overwrites d_out fully (supB/wTp dead — props read the supP copy).
// d_in[0] (x, 102.4MB) = scratch AFTER gemm (sole reader of x). d_ws unused.
// Harness restores d_in before every launch.
// ---------------------------------------------------------------------------
extern "C" void kernel_launch(void* const* d_in, const int* in_sizes, int n_in,
                              void* d_out, int out_size, void* d_ws, size_t ws_size,
                              hipStream_t stream) {
    const float* x    = (const float*)d_in[0];
    const float* w    = (const float*)d_in[1];
    const int*   esrc = (const int*)d_in[2];
    const int*   edst = (const int*)d_in[3];
    const float* eval = (const float*)d_in[4];
    float* out = (float*)d_out;

    const size_t supBytes = (size_t)N_NODES * OUT_F * sizeof(ushort);  // 9.6MB
    ushort* supB = (ushort*)d_out;
    ushort* wTp  = (ushort*)((char*)d_out + (size_t)out_size * 4
                             - (size_t)IN_F * OUT_F * sizeof(ushort));

    char*  xb  = (char*)d_in[0];
    size_t off = 0;
    auto alloc = [&](size_t bytes) -> char* {
        char* p = xb + off;
        off = (off + bytes + 255) & ~(size_t)255;
        return p;
    };
    ushort* supP      = (ushort*)alloc(supBytes);                      // 9.6MB
    ushort* hU        = (ushort*)alloc(supBytes);                      // 9.6MB
    ushort* hV        = (ushort*)alloc(supBytes);                      // 9.6MB
    uint*   edgeE     = (uint*)alloc((size_t)N_EDGES * sizeof(uint));  // 3.2MB
    int*    rowstart  = (int*)alloc((N_NODES + 1) * sizeof(int));
    int*    cursor    = (int*)alloc(N_NODES * sizeof(int));
    int*    counts    = (int*)alloc((N_NODES + DEGBINS) * sizeof(int));
    int*    deghist   = counts + N_NODES;
    int*    blockSums = (int*)alloc(SCAN_BLOCKS * sizeof(int));
    int*    blockOffs = (int*)alloc(SCAN_BLOCKS * sizeof(int));
    int*    degcur    = (int*)alloc(DEGBINS * sizeof(int));
    int*    perm      = (int*)alloc(N_NODES * sizeof(int));            // 200KB
    // ~34MB << 102.4MB

    // 1) weights -> bf16 chunk-major (d_out top)
    wt_kernel<<<(IN_F * OUT_F + 255) / 256, 256, 0, stream>>>(w, wTp);

    // 2) MFMA GEMM (last reader of x) -> supB in d_out
    gemm_kernel<<<(N_NODES + 15) / 16, 64, 0, stream>>>(x, wTp, supB);

    // 3) copy supB into x-scratch so final prop can freely write d_out
    (void)hipMemcpyAsync(supP, supB, supBytes, hipMemcpyDeviceToDevice, stream);

    // 4) CSR build + degree counting-sort (x-scratch; safe post-gemm)
    zero_kernel<<<(N_NODES + DEGBINS + 255) / 256, 256, 0, stream>>>(
        counts, N_NODES + DEGBINS);
    hist_kernel<<<(N_EDGES + 255) / 256, 256, 0, stream>>>(edst, counts);
    block_reduce_kernel<<<SCAN_BLOCKS, 256, 0, stream>>>(counts, blockSums);
    scan_sums_kernel<<<1, 256, 0, stream>>>(blockSums, blockOffs, rowstart);
    block_scan_kernel<<<SCAN_BLOCKS, 256, 0, stream>>>(counts, blockOffs,
                                                       rowstart, cursor, deghist);
    degscan_kernel<<<1, 256, 0, stream>>>(deghist, degcur);
    degscatter_kernel<<<SCAN_BLOCKS, 256, 0, stream>>>(counts, degcur, perm);
    scatter_kernel<<<(N_EDGES + 255) / 256, 256, 0, stream>>>(esrc, edst, eval,
                                                              cursor, edgeE);

    // 5) 10 propagation iterations: supP -> hU -> hV -> ... -> d_out (fp32)
    const int pgrid = (N_NODES * TPN + 255) / 256;
    const ushort* in = supP;
    for (int it = 1; it <= 9; ++it) {
        ushort* o = (it & 1) ? hU : hV;
        prop_kernel<false><<<pgrid, 256, 0, stream>>>(in, supP, rowstart, edgeE,
                                                      perm, o, nullptr);
        in = o;
    }
    prop_kernel<true><<<pgrid, 256, 0, stream>>>(in, supP, rowstart, edgeE,
                                                 perm, nullptr, out);
}

// Round 11
// 531.302 us; speedup vs baseline: 1.3472x; 1.0184x over previous
//
#include <hip/hip_runtime.h>

typedef unsigned int   uint;
typedef unsigned short ushort;
typedef __attribute__((ext_vector_type(8))) short bf16x8;   // 8 bf16 (4 VGPRs)
typedef __attribute__((ext_vector_type(4))) float f32x4;

#define N_NODES 50000
#define N_EDGES 800000
#define IN_F    512
#define OUT_F   96
#define SCAN_BLOCKS 196   // 196*256 >= 50000
#define TPN 12            // threads per node in prop (96 feats / 8 per lane)
#define DEGBINS 256       // counting-sort bins for degree sort

// bf16 helpers (storage-only bf16; math in fp32)
__device__ __forceinline__ float bflo(uint u) { return __uint_as_float(u << 16); }
__device__ __forceinline__ float bfhi(uint u) { return __uint_as_float(u & 0xffff0000u); }
__device__ __forceinline__ uint f2bf(float x) {          // round-to-nearest-even
    uint u = __float_as_uint(x);
    return (u + 0x7fffu + ((u >> 16) & 1u)) >> 16;
}
__device__ __forceinline__ uint pack2bf(float lo, float hi) {
    return f2bf(lo) | (f2bf(hi) << 16);
}

// ---------------------------------------------------------------------------
// w[512,96] fp32 -> wTp chunk-major bf16: wTp[k/32][c][k%32].
// ---------------------------------------------------------------------------
__global__ __launch_bounds__(256) void wt_kernel(const float* __restrict__ w,
                                                 ushort* __restrict__ wTp) {
    int t = blockIdx.x * 256 + threadIdx.x;
    if (t < IN_F * OUT_F) {
        int k = t / OUT_F, c = t - k * OUT_F;
        wTp[(size_t)(k >> 5) * (OUT_F * 32) + c * 32 + (k & 31)] =
            (ushort)f2bf(w[t]);
    }
}

// ---------------------------------------------------------------------------
// MFMA GEMM: supB[N,96](bf16) = x[N,512] @ w[512,96]  (row-major, R2-exact)
// ---------------------------------------------------------------------------
__global__ __launch_bounds__(64) void gemm_kernel(const float* __restrict__ x,
                                                  const ushort* __restrict__ wTp,
                                                  ushort* __restrict__ supB) {
    const int lane = threadIdx.x;
    const int m    = lane & 15;
    const int quad = lane >> 4;

    const int row  = blockIdx.x * 16 + m;
    const int arow = (row < N_NODES) ? row : (N_NODES - 1);
    const float*  xp = x + (size_t)arow * IN_F + quad * 8;
    const ushort* wp = wTp + (size_t)m * 32 + quad * 8;   // chunk 0 base

    f32x4 acc[6];
    #pragma unroll
    for (int ct = 0; ct < 6; ++ct) acc[ct] = (f32x4){0.f, 0.f, 0.f, 0.f};

    // prologue: x chunks 0,1 and w chunk 0 in flight
    float4 xA0 = *(const float4*)(xp);
    float4 xB0 = *(const float4*)(xp + 4);
    float4 xA1 = *(const float4*)(xp + 32);
    float4 xB1 = *(const float4*)(xp + 36);
    bf16x8 b[6];
    #pragma unroll
    for (int ct = 0; ct < 6; ++ct)
        b[ct] = *(const bf16x8*)(wp + ct * (16 * 32));

    #pragma unroll
    for (int it = 0; it < 16; ++it) {
        float4 nxa, nxb;
        bf16x8 nb[6];
        if (it + 2 < 16) {
            nxa = *(const float4*)(xp + (it + 2) * 32);
            nxb = *(const float4*)(xp + (it + 2) * 32 + 4);
        }
        if (it + 1 < 16) {
            const ushort* wpn = wp + (size_t)(it + 1) * (OUT_F * 32);
            #pragma unroll
            for (int ct = 0; ct < 6; ++ct)
                nb[ct] = *(const bf16x8*)(wpn + ct * (16 * 32));
        }
        union { uint u[4]; bf16x8 v; } af;
        af.u[0] = pack2bf(xA0.x, xA0.y); af.u[1] = pack2bf(xA0.z, xA0.w);
        af.u[2] = pack2bf(xB0.x, xB0.y); af.u[3] = pack2bf(xB0.z, xB0.w);
        #pragma unroll
        for (int ct = 0; ct < 6; ++ct)
            acc[ct] = __builtin_amdgcn_mfma_f32_16x16x32_bf16(af.v, b[ct],
                                                              acc[ct], 0, 0, 0);
        xA0 = xA1; xB0 = xB1; xA1 = nxa; xB1 = nxb;
        #pragma unroll
        for (int ct = 0; ct < 6; ++ct) b[ct] = nb[ct];
    }

    // C/D layout: col = lane&15 (=m), row = quad*4 + reg
    const int orow0 = blockIdx.x * 16 + quad * 4;
    #pragma unroll
    for (int ct = 0; ct < 6; ++ct) {
        #pragma unroll
        for (int r = 0; r < 4; ++r) {
            int gr = orow0 + r;
            if (gr < N_NODES)
                supB[(size_t)gr * OUT_F + ct * 16 + m] = (ushort)f2bf(acc[ct][r]);
        }
    }
}

// ---------------------------------------------------------------------------
// CSR build: histogram -> hierarchical scan -> scatter (4B packed edges:
// low 16 bits = src node id (50000 < 65536), high 16 bits = bf16 edge val)
// Degree counting-sort via LDS-aggregated histograms (R1 lesson: naive
// global atomics on ~30 hot bins serialized to 131us).
// ---------------------------------------------------------------------------
__global__ void zero_kernel(int* __restrict__ p, int n) {
    int t = blockIdx.x * blockDim.x + threadIdx.x;
    if (t < n) p[t] = 0;
}

__global__ void hist_kernel(const int* __restrict__ dst, int* __restrict__ counts) {
    int e = blockIdx.x * blockDim.x + threadIdx.x;
    if (e < N_EDGES) atomicAdd(&counts[dst[e]], 1);
}

__global__ __launch_bounds__(256) void block_reduce_kernel(const int* __restrict__ counts,
                                                           int* __restrict__ blockSums) {
    __shared__ int s[256];
    int idx = blockIdx.x * 256 + threadIdx.x;
    s[threadIdx.x] = (idx < N_NODES) ? counts[idx] : 0;
    __syncthreads();
    for (int off = 128; off > 0; off >>= 1) {
        if (threadIdx.x < off) s[threadIdx.x] += s[threadIdx.x + off];
        __syncthreads();
    }
    if (threadIdx.x == 0) blockSums[blockIdx.x] = s[0];
}

__global__ __launch_bounds__(256) void scan_sums_kernel(int* __restrict__ blockSums,
                                                        int* __restrict__ blockOffs,
                                                        int* __restrict__ rowstart) {
    __shared__ int s[256];
    int t = threadIdx.x;
    s[t] = (t < SCAN_BLOCKS) ? blockSums[t] : 0;
    __syncthreads();
    for (int off = 1; off < 256; off <<= 1) {
        int v = (t >= off) ? s[t - off] : 0;
        __syncthreads();
        s[t] += v;
        __syncthreads();
    }
    if (t < SCAN_BLOCKS) blockOffs[t] = (t == 0) ? 0 : s[t - 1];
    if (t == 0) rowstart[N_NODES] = s[SCAN_BLOCKS - 1];
}

__global__ __launch_bounds__(256) void block_scan_kernel(const int* __restrict__ counts,
                                                         const int* __restrict__ blockOffs,
                                                         int* __restrict__ rowstart,
                                                         int* __restrict__ cursor,
                                                         int* __restrict__ deghist) {
    __shared__ int s[256];
    __shared__ int lh[DEGBINS];
    int t   = threadIdx.x;
    int idx = blockIdx.x * 256 + t;
    int v   = (idx < N_NODES) ? counts[idx] : 0;
    s[t]  = v;
    lh[t] = 0;
    __syncthreads();
    for (int off = 1; off < 256; off <<= 1) {
        int u = (t >= off) ? s[t - off] : 0;
        __syncthreads();
        s[t] += u;
        __syncthreads();
    }
    if (idx < N_NODES) {
        int excl = blockOffs[blockIdx.x] + s[t] - v;
        rowstart[idx] = excl;
        cursor[idx]   = excl;
        int d = v < (DEGBINS - 1) ? v : (DEGBINS - 1);
        atomicAdd(&lh[d], 1);                 // LDS-aggregated degree histogram
    }
    __syncthreads();
    if (lh[t] > 0) atomicAdd(&deghist[t], lh[t]);   // <=196 adds per address
}

// single block: exclusive scan of the 256 degree bins -> scatter cursors
__global__ __launch_bounds__(256) void degscan_kernel(const int* __restrict__ deghist,
                                                      int* __restrict__ degcur) {
    __shared__ int s[256];
    int t = threadIdx.x;
    int v = deghist[t];
    s[t] = v;
    __syncthreads();
    for (int off = 1; off < 256; off <<= 1) {
        int u = (t >= off) ? s[t - off] : 0;
        __syncthreads();
        s[t] += u;
        __syncthreads();
    }
    degcur[t] = s[t] - v;                     // exclusive prefix
}

// perm grouped by degree, DESCENDING (LPT schedule): pos is ascending-degree
// rank; writing to perm[N-1-pos] reverses it so the heaviest nodes land in
// the FIRST blocks of each prop launch and light nodes back-fill the tail.
// Wave degree-uniformity is preserved (equal-degree runs stay contiguous).
__global__ __launch_bounds__(256) void degscatter_kernel(const int* __restrict__ counts,
                                                         int* __restrict__ degcur,
                                                         int* __restrict__ perm) {
    __shared__ int lhist[DEGBINS];
    __shared__ int lbase[DEGBINS];
    int t = threadIdx.x;
    lhist[t] = 0;
    __syncthreads();
    int i = blockIdx.x * 256 + t;
    int d = 0, lr = 0;
    bool valid = (i < N_NODES);
    if (valid) {
        d  = counts[i];
        if (d > DEGBINS - 1) d = DEGBINS - 1;
        lr = atomicAdd(&lhist[d], 1);         // within-block rank (LDS atomic)
    }
    __syncthreads();
    if (lhist[t] > 0) lbase[t] = atomicAdd(&degcur[t], lhist[t]);
    __syncthreads();
    if (valid) perm[(N_NODES - 1) - (lbase[d] + lr)] = i;
}

__global__ void scatter_kernel(const int* __restrict__ src, const int* __restrict__ dst,
                               const float* __restrict__ val, int* __restrict__ cursor,
                               uint* __restrict__ edgeE) {
    int e = blockIdx.x * blockDim.x + threadIdx.x;
    if (e < N_EDGES) {
        int d   = dst[e];
        int pos = atomicAdd(&cursor[d], 1);
        edgeE[pos] = (f2bf(val[e]) << 16) | (uint)src[e];
    }
}

// ---------------------------------------------------------------------------
// Propagation (R2-exact structure; R10 fast path reverted as null): thread
// t -> sorted-slot i = t/12 -> node perm[i] (degree-sorted descending: waves
// are degree-uniform AND heavy blocks launch first = LPT), octet q = t%12.
// Main loop: 8-edge chunks, edge records double-buffered. Tail: one masked
// 8-wide chunk. No cache hints (R6/R9 lessons: nt poisoned reuse both times).
// FMA order per (node,feature) identical to R2 -> bitwise-identical output.
// ---------------------------------------------------------------------------
__device__ __forceinline__ void acc8(float* a, float v, uint4 hv) {
    a[0] = fmaf(v, bflo(hv.x), a[0]); a[1] = fmaf(v, bfhi(hv.x), a[1]);
    a[2] = fmaf(v, bflo(hv.y), a[2]); a[3] = fmaf(v, bfhi(hv.y), a[3]);
    a[4] = fmaf(v, bflo(hv.z), a[4]); a[5] = fmaf(v, bfhi(hv.z), a[5]);
    a[6] = fmaf(v, bflo(hv.w), a[6]); a[7] = fmaf(v, bfhi(hv.w), a[7]);
}

template <bool FINAL>
__global__ __launch_bounds__(256) void prop_kernel(const ushort* __restrict__ h,
                                                   const ushort* __restrict__ sup,
                                                   const int* __restrict__ rowstart,
                                                   const uint* __restrict__ edgeE,
                                                   const int* __restrict__ perm,
                                                   ushort* __restrict__ outB,
                                                   float* __restrict__ outF) {
    int t = blockIdx.x * 256 + threadIdx.x;
    int i = t / TPN;
    if (i >= N_NODES) return;
    int q = t - i * TPN;
    int f = q * 8;
    int node = perm[i];

    int start = rowstart[node];
    int end   = rowstart[node + 1];

    size_t o = (size_t)node * OUT_F + f;
    uint4 sp = *(const uint4*)(sup + o);      // prefetch: hides epilogue latency

    float a[8] = {0.f, 0.f, 0.f, 0.f, 0.f, 0.f, 0.f, 0.f};
    int e  = start;
    int n8 = (end - start) >> 3;

    uint ed[8];
    if (n8 > 0) {
        #pragma unroll
        for (int u = 0; u < 8; ++u) ed[u] = edgeE[start + u];
    }
    for (int c = 0; c < n8; ++c) {
        uint4 hv[8];
        #pragma unroll
        for (int u = 0; u < 8; ++u)
            hv[u] = *(const uint4*)(h + (size_t)(ed[u] & 0xffffu) * OUT_F + f);
        uint edc[8];
        #pragma unroll
        for (int u = 0; u < 8; ++u) edc[u] = ed[u];
        if (c + 1 < n8) {                     // prefetch next chunk's edges;
            #pragma unroll                    // they ride out the FMA block
            for (int u = 0; u < 8; ++u) ed[u] = edgeE[e + 8 + u];
        }
        #pragma unroll
        for (int u = 0; u < 8; ++u) acc8(a, bfhi(edc[u]), hv[u]);
        e += 8;
    }

    int rem = end - e;
    if (rem > 0) {                            // one masked 8-wide chunk
        uint edt[8];
        #pragma unroll
        for (int u = 0; u < 8; ++u) {
            int ee = e + u;
            edt[u] = edgeE[(ee < end) ? ee : (end - 1)];
        }
        uint4 hv[8];
        #pragma unroll
        for (int u = 0; u < 8; ++u)
            hv[u] = *(const uint4*)(h + (size_t)(edt[u] & 0xffffu) * OUT_F + f);
        #pragma unroll
        for (int u = 0; u < 8; ++u) {
            float v = (u < rem) ? bfhi(edt[u]) : 0.f;
            acc8(a, v, hv[u]);
        }
    }

    float r[8];
    r[0] = fmaxf(fmaf(a[0], 0.9f, bflo(sp.x) * 0.1f), 0.f);
    r[1] = fmaxf(fmaf(a[1], 0.9f, bfhi(sp.x) * 0.1f), 0.f);
    r[2] = fmaxf(fmaf(a[2], 0.9f, bflo(sp.y) * 0.1f), 0.f);
    r[3] = fmaxf(fmaf(a[3], 0.9f, bfhi(sp.y) * 0.1f), 0.f);
    r[4] = fmaxf(fmaf(a[4], 0.9f, bflo(sp.z) * 0.1f), 0.f);
    r[5] = fmaxf(fmaf(a[5], 0.9f, bfhi(sp.z) * 0.1f), 0.f);
    r[6] = fmaxf(fmaf(a[6], 0.9f, bflo(sp.w) * 0.1f), 0.f);
    r[7] = fmaxf(fmaf(a[7], 0.9f, bfhi(sp.w) * 0.1f), 0.f);

    if (FINAL) {
        *(float4*)(outF + o)     = make_float4(r[0], r[1], r[2], r[3]);
        *(float4*)(outF + o + 4) = make_float4(r[4], r[5], r[6], r[7]);
    } else {
        *(uint4*)(outB + o) = make_uint4(pack2bf(r[0], r[1]), pack2bf(r[2], r[3]),
                                         pack2bf(r[4], r[5]), pack2bf(r[6], r[7]));
    }
}

// ---------------------------------------------------------------------------
// Buffers: d_out low 9.6MB = supB (gemm out), top 98KB = wTp; final prop
// overwrites d_out fully (supB/wTp dead — props read the supP copy).
// d_in[0] (x, 102.4MB) = scratch AFTER gemm (sole reader of x). d_ws unused.
// Harness restores d_in before every launch.
// ---------------------------------------------------------------------------
extern "C" void kernel_launch(void* const* d_in, const int* in_sizes, int n_in,
                              void* d_out, int out_size, void* d_ws, size_t ws_size,
                              hipStream_t stream) {
    const float* x    = (const float*)d_in[0];
    const float* w    = (const float*)d_in[1];
    const int*   esrc = (const int*)d_in[2];
    const int*   edst = (const int*)d_in[3];
    const float* eval = (const float*)d_in[4];
    float* out = (float*)d_out;

    const size_t supBytes = (size_t)N_NODES * OUT_F * sizeof(ushort);  // 9.6MB
    ushort* supB = (ushort*)d_out;
    ushort* wTp  = (ushort*)((char*)d_out + (size_t)out_size * 4
                             - (size_t)IN_F * OUT_F * sizeof(ushort));

    char*  xb  = (char*)d_in[0];
    size_t off = 0;
    auto alloc = [&](size_t bytes) -> char* {
        char* p = xb + off;
        off = (off + bytes + 255) & ~(size_t)255;
        return p;
    };
    ushort* supP      = (ushort*)alloc(supBytes);                      // 9.6MB
    ushort* hU        = (ushort*)alloc(supBytes);                      // 9.6MB
    ushort* hV        = (ushort*)alloc(supBytes);                      // 9.6MB
    uint*   edgeE     = (uint*)alloc((size_t)N_EDGES * sizeof(uint));  // 3.2MB
    int*    rowstart  = (int*)alloc((N_NODES + 1) * sizeof(int));
    int*    cursor    = (int*)alloc(N_NODES * sizeof(int));
    int*    counts    = (int*)alloc((N_NODES + DEGBINS) * sizeof(int));
    int*    deghist   = counts + N_NODES;
    int*    blockSums = (int*)alloc(SCAN_BLOCKS * sizeof(int));
    int*    blockOffs = (int*)alloc(SCAN_BLOCKS * sizeof(int));
    int*    degcur    = (int*)alloc(DEGBINS * sizeof(int));
    int*    perm      = (int*)alloc(N_NODES * sizeof(int));            // 200KB
    // ~34MB << 102.4MB

    // 1) weights -> bf16 chunk-major (d_out top)
    wt_kernel<<<(IN_F * OUT_F + 255) / 256, 256, 0, stream>>>(w, wTp);

    // 2) MFMA GEMM (last reader of x) -> supB in d_out
    gemm_kernel<<<(N_NODES + 15) / 16, 64, 0, stream>>>(x, wTp, supB);

    // 3) copy supB into x-scratch so final prop can freely write d_out
    (void)hipMemcpyAsync(supP, supB, supBytes, hipMemcpyDeviceToDevice, stream);

    // 4) CSR build + degree counting-sort (x-scratch; safe post-gemm)
    zero_kernel<<<(N_NODES + DEGBINS + 255) / 256, 256, 0, stream>>>(
        counts, N_NODES + DEGBINS);
    hist_kernel<<<(N_EDGES + 255) / 256, 256, 0, stream>>>(edst, counts);
    block_reduce_kernel<<<SCAN_BLOCKS, 256, 0, stream>>>(counts, blockSums);
    scan_sums_kernel<<<1, 256, 0, stream>>>(blockSums, blockOffs, rowstart);
    block_scan_kernel<<<SCAN_BLOCKS, 256, 0, stream>>>(counts, blockOffs,
                                                       rowstart, cursor, deghist);
    degscan_kernel<<<1, 256, 0, stream>>>(deghist, degcur);
    degscatter_kernel<<<SCAN_BLOCKS, 256, 0, stream>>>(counts, degcur, perm);
    scatter_kernel<<<(N_EDGES + 255) / 256, 256, 0, stream>>>(esrc, edst, eval,
                                                              cursor, edgeE);

    // 5) 10 propagation iterations: supP -> hU -> hV -> ... -> d_out (fp32)
    const int pgrid = (N_NODES * TPN + 255) / 256;
    const ushort* in = supP;
    for (int it = 1; it <= 9; ++it) {
        ushort* o = (it & 1) ? hU : hV;
        prop_kernel<false><<<pgrid, 256, 0, stream>>>(in, supP, rowstart, edgeE,
                                                      perm, o, nullptr);
        in = o;
    }
    prop_kernel<true><<<pgrid, 256, 0, stream>>>(in, supP, rowstart, edgeE,
                                                 perm, nullptr, out);
}